// Round 2
// baseline (526.908 us; speedup 1.0000x reference)
//
#include <hip/hip_runtime.h>
#include <hip/hip_bf16.h>
#include <stdint.h>

#define N_LGN   17400
#define N_POST  50000
#define NNZ     800000
#define N_BASIS 5
#define ELL_CAP 48

#define TPOSE_CBLK   32
#define TPOSE_BLOCKS ((N_LGN + TPOSE_CBLK - 1) / TPOSE_CBLK)   // 544
#define SCAT_THREADS (NNZ / 4)                                  // 200000 (4 edges/thread)
#define SCAT_BLOCKS  ((SCAT_THREADS + 255) / 256)               // 782

// ---------------- fused prep: scatter (blocks [0,782)) + transpose (blocks [782,1326)) ----
__global__ __launch_bounds__(256) void k_prep(const float* __restrict__ inp,
                                              __hip_bfloat162* __restrict__ xTb,
                                              const int4* __restrict__ idx4,
                                              const float4* __restrict__ w4,
                                              const int4* __restrict__ syn4,
                                              int* __restrict__ counts,
                                              int2* __restrict__ ell) {
    __shared__ float tile[TPOSE_CBLK * 129];
    int tid = threadIdx.x;
    if (blockIdx.x < SCAT_BLOCKS) {
        int t = blockIdx.x * 256 + tid;
        if (t >= SCAT_THREADS) return;
        int4 iA = idx4[2 * t];          // edges 4t,4t+1: (row,col,row,col)
        int4 iB = idx4[2 * t + 1];      // edges 4t+2,4t+3
        float4 ww = w4[t];
        int4 sy = syn4[t];
        int r0 = atomicAdd(&counts[iA.x], 1);
        if (r0 < ELL_CAP) ell[iA.x * ELL_CAP + r0] = make_int2(iA.y | (sy.x << 16), __float_as_int(ww.x));
        int r1 = atomicAdd(&counts[iA.z], 1);
        if (r1 < ELL_CAP) ell[iA.z * ELL_CAP + r1] = make_int2(iA.w | (sy.y << 16), __float_as_int(ww.y));
        int r2 = atomicAdd(&counts[iB.x], 1);
        if (r2 < ELL_CAP) ell[iB.x * ELL_CAP + r2] = make_int2(iB.y | (sy.z << 16), __float_as_int(ww.z));
        int r3 = atomicAdd(&counts[iB.z], 1);
        if (r3 < ELL_CAP) ell[iB.z * ELL_CAP + r3] = make_int2(iB.w | (sy.w << 16), __float_as_int(ww.w));
    } else {
        int c0 = (blockIdx.x - SCAT_BLOCKS) * TPOSE_CBLK;
        for (int it = 0; it < 16; ++it) {
            int flat = it * 256 + tid;
            int s  = flat >> 5;
            int cl = flat & 31;
            int c  = c0 + cl;
            float v = 0.0f;
            if (c < N_LGN) v = inp[s * N_LGN + c];
            tile[cl * 129 + s] = v;
        }
        __syncthreads();
        for (int it = 0; it < 8; ++it) {
            int flat = it * 256 + tid;
            int cl = flat >> 6;
            int sp = flat & 63;
            int c  = c0 + cl;
            if (c < N_LGN) {
                float2 f = make_float2(tile[cl * 129 + 2 * sp], tile[cl * 129 + 2 * sp + 1]);
                xTb[c * 64 + sp] = __float22bfloat162_rn(f);
            }
        }
    }
}

// ---------------- CSR fallback path (used only if ws too small for ELL) ----------------
__global__ __launch_bounds__(256) void k_transpose_bf16(const float* __restrict__ inp,
                                                        __hip_bfloat162* __restrict__ xTb) {
    __shared__ float tile[64 * 129];
    int c0  = blockIdx.x * 64;
    int tid = threadIdx.x;
    for (int it = 0; it < 32; ++it) {
        int flat = it * 256 + tid;
        int s  = flat >> 6;
        int cl = flat & 63;
        int c  = c0 + cl;
        float v = 0.0f;
        if (c < N_LGN) v = inp[s * N_LGN + c];
        tile[cl * 129 + s] = v;
    }
    __syncthreads();
    for (int it = 0; it < 16; ++it) {
        int flat = it * 256 + tid;
        int cl = flat >> 6;
        int sp = flat & 63;
        int c  = c0 + cl;
        if (c < N_LGN) {
            float2 f = make_float2(tile[cl * 129 + 2 * sp], tile[cl * 129 + 2 * sp + 1]);
            xTb[c * 64 + sp] = __float22bfloat162_rn(f);
        }
    }
}

__global__ __launch_bounds__(256) void k_hist(const int4* __restrict__ idx2,
                                              int* __restrict__ counts) {
    int t = blockIdx.x * 256 + threadIdx.x;
    if (t >= NNZ / 2) return;
    int4 rc = idx2[t];
    atomicAdd(&counts[rc.x], 1);
    atomicAdd(&counts[rc.z], 1);
}

__global__ __launch_bounds__(1024) void k_scan1(const int* __restrict__ counts,
                                                int* __restrict__ rowStart,
                                                int* __restrict__ blockSums) {
    __shared__ int tmp[1024];
    int tid = threadIdx.x;
    int gid = blockIdx.x * 1024 + tid;
    int v = (gid < N_POST) ? counts[gid] : 0;
    tmp[tid] = v;
    __syncthreads();
    for (int off = 1; off < 1024; off <<= 1) {
        int t = (tid >= off) ? tmp[tid - off] : 0;
        __syncthreads();
        tmp[tid] += t;
        __syncthreads();
    }
    if (gid < N_POST) rowStart[gid] = tmp[tid] - v;
    if (tid == 1023) blockSums[blockIdx.x] = tmp[1023];
}

__global__ __launch_bounds__(64) void k_scan2(const int* __restrict__ blockSums,
                                              int* __restrict__ blockOffsets, int nblk) {
    __shared__ int tmp[64];
    int tid = threadIdx.x;
    int v = (tid < nblk) ? blockSums[tid] : 0;
    tmp[tid] = v;
    __syncthreads();
    for (int off = 1; off < 64; off <<= 1) {
        int t = (tid >= off) ? tmp[tid - off] : 0;
        __syncthreads();
        tmp[tid] += t;
        __syncthreads();
    }
    if (tid < nblk) blockOffsets[tid] = tmp[tid] - v;
}

__global__ __launch_bounds__(1024) void k_scan3(int* __restrict__ rowStart,
                                                const int* __restrict__ blockOffsets) {
    int gid = blockIdx.x * 1024 + threadIdx.x;
    if (gid < N_POST) rowStart[gid] += blockOffsets[blockIdx.x];
}

__global__ __launch_bounds__(256) void k_scatter_csr(const int4* __restrict__ idx2,
                                                     const float2* __restrict__ w2,
                                                     const int2* __restrict__ syn2,
                                                     const int* __restrict__ rowStart,
                                                     int* __restrict__ cursor,
                                                     int2* __restrict__ edges) {
    int t = blockIdx.x * 256 + threadIdx.x;
    if (t >= NNZ / 2) return;
    int4 rc = idx2[t];
    float2 ww = w2[t];
    int2 sy = syn2[t];
    int p0 = rowStart[rc.x] + atomicAdd(&cursor[rc.x], 1);
    edges[p0] = make_int2(rc.y | (sy.x << 16), __float_as_int(ww.x));
    int p1 = rowStart[rc.z] + atomicAdd(&cursor[rc.z], 1);
    edges[p1] = make_int2(rc.w | (sy.y << 16), __float_as_int(ww.y));
}

// ---------------- main compute: balanced cooperative block ------------------------------
// Block = 8 rows, 8 waves. The 8 rows' edge lists are treated as one concatenated stream
// of E edges; wave w processes the slice [E*w/8, E*(w+1)/8) regardless of row boundaries.
// Removes the max-of-8-Poisson barrier inflation (~36%) that kept VALUBusy at 37%.
// Row-partial accumulators are flushed into LDS via atomicAdd on boundary crossings
// (<= ~3 flushes per wave).
__global__ __launch_bounds__(512, 6) void k_compute(const __hip_bfloat162* __restrict__ xTb,
                                                    const int2* __restrict__ edges,
                                                    const int* __restrict__ rowStart,
                                                    const int* __restrict__ counts,
                                                    const float* __restrict__ sw,
                                                    float2* __restrict__ out2,
                                                    int cap, int useEll) {
    __shared__ float facs[64];              // synaptic_weights: 10x5 = 50 floats
    __shared__ float accLds[40 * 133];      // [j = rowLocal*5+r][s], pitch 133
    __shared__ int   offS[9];               // block-local exclusive prefix of row counts
    int tid  = threadIdx.x;
    int wave = tid >> 6;
    int lane = tid & 63;
    int n0   = blockIdx.x * 8;              // 6250*8 == 50000 exactly

    if (tid < 50) facs[tid] = sw[tid];
    for (int i = tid; i < 40 * 133; i += 512) accLds[i] = 0.0f;   // zero accumulators
    __syncthreads();
    if (tid == 0) {
        int acc = 0;
        for (int k = 0; k < 8; ++k) {
            offS[k] = acc;
            int c = counts[n0 + k];
            if (c > cap) c = cap;
            acc += c;
        }
        offS[8] = acc;
    }
    __syncthreads();

    int E  = offS[8];
    int g  = (E * wave) >> 3;               // this wave's balanced slice
    int g1 = (E * (wave + 1)) >> 3;

    float a0[N_BASIS] = {0.f, 0.f, 0.f, 0.f, 0.f};
    float a1[N_BASIS] = {0.f, 0.f, 0.f, 0.f, 0.f};

    if (g < g1) {
        // locate starting row k: off[k] <= g < off[k+1]  (wave-uniform)
        int k = 0;
        while (offS[k + 1] <= g) ++k;
        while (g < g1) {
            int segEnd = offS[k + 1];
            if (segEnd > g1) segEnd = g1;
            int rowBase = useEll ? (n0 + k) * cap : rowStart[n0 + k];
            const int2* ep = edges + rowBase + (g - offS[k]);
            int m = segEnd - g;
            int j = 0;
            for (; j + 3 < m; j += 4) {     // 4 independent gathers in flight
                int2 e0 = ep[j];
                int2 e1 = ep[j + 1];
                int2 e2 = ep[j + 2];
                int2 e3 = ep[j + 3];
                int c0 = e0.x & 0xFFFF, sy0 = e0.x >> 16;
                int c1 = e1.x & 0xFFFF, sy1 = e1.x >> 16;
                int c2 = e2.x & 0xFFFF, sy2 = e2.x >> 16;
                int c3 = e3.x & 0xFFFF, sy3 = e3.x >> 16;
                float2 x0 = __bfloat1622float2(xTb[c0 * 64 + lane]);   // 256B/wave coalesced
                float2 x1 = __bfloat1622float2(xTb[c1 * 64 + lane]);
                float2 x2 = __bfloat1622float2(xTb[c2 * 64 + lane]);
                float2 x3 = __bfloat1622float2(xTb[c3 * 64 + lane]);
                float w0 = __int_as_float(e0.y);
                float w1 = __int_as_float(e1.y);
                float w2 = __int_as_float(e2.y);
                float w3 = __int_as_float(e3.y);
#pragma unroll
                for (int r = 0; r < N_BASIS; ++r) {
                    float f0 = w0 * facs[sy0 * 5 + r];   // wave-uniform LDS: broadcast
                    float f1 = w1 * facs[sy1 * 5 + r];
                    float f2 = w2 * facs[sy2 * 5 + r];
                    float f3 = w3 * facs[sy3 * 5 + r];
                    a0[r] = fmaf(x0.x, f0, a0[r]);  a1[r] = fmaf(x0.y, f0, a1[r]);
                    a0[r] = fmaf(x1.x, f1, a0[r]);  a1[r] = fmaf(x1.y, f1, a1[r]);
                    a0[r] = fmaf(x2.x, f2, a0[r]);  a1[r] = fmaf(x2.y, f2, a1[r]);
                    a0[r] = fmaf(x3.x, f3, a0[r]);  a1[r] = fmaf(x3.y, f3, a1[r]);
                }
            }
            for (; j + 1 < m; j += 2) {
                int2 e0 = ep[j];
                int2 e1 = ep[j + 1];
                int c0 = e0.x & 0xFFFF, sy0 = e0.x >> 16;
                int c1 = e1.x & 0xFFFF, sy1 = e1.x >> 16;
                float2 x0 = __bfloat1622float2(xTb[c0 * 64 + lane]);
                float2 x1 = __bfloat1622float2(xTb[c1 * 64 + lane]);
                float w0 = __int_as_float(e0.y);
                float w1 = __int_as_float(e1.y);
#pragma unroll
                for (int r = 0; r < N_BASIS; ++r) {
                    float f0 = w0 * facs[sy0 * 5 + r];
                    float f1 = w1 * facs[sy1 * 5 + r];
                    a0[r] = fmaf(x0.x, f0, a0[r]);  a1[r] = fmaf(x0.y, f0, a1[r]);
                    a0[r] = fmaf(x1.x, f1, a0[r]);  a1[r] = fmaf(x1.y, f1, a1[r]);
                }
            }
            if (j < m) {
                int2 e0 = ep[j];
                int c0 = e0.x & 0xFFFF, sy0 = e0.x >> 16;
                float2 x0 = __bfloat1622float2(xTb[c0 * 64 + lane]);
                float w0 = __int_as_float(e0.y);
#pragma unroll
                for (int r = 0; r < N_BASIS; ++r) {
                    float f0 = w0 * facs[sy0 * 5 + r];
                    a0[r] = fmaf(x0.x, f0, a0[r]);
                    a1[r] = fmaf(x0.y, f0, a1[r]);
                }
            }
            // flush this row's partial sums (few waves share a boundary row -> low contention)
#pragma unroll
            for (int r = 0; r < N_BASIS; ++r) {
                int jj = k * 5 + r;
                atomicAdd(&accLds[jj * 133 + 2 * lane],     a0[r]);
                atomicAdd(&accLds[jj * 133 + 2 * lane + 1], a1[r]);
                a0[r] = 0.0f;
                a1[r] = 0.0f;
            }
            g = segEnd;
            ++k;
        }
    }
    __syncthreads();

    // epilogue: 128 s x 40 floats = 2560 float2; contiguous 160B runs per s
    int base2 = blockIdx.x * 20;
    for (int it = 0; it < 5; ++it) {
        int flat = it * 512 + tid;          // 0..2559
        int s  = flat / 20;
        int jj = flat % 20;
        float f0 = accLds[(2 * jj) * 133 + s];
        float f1 = accLds[(2 * jj + 1) * 133 + s];
        out2[s * 125000 + base2 + jj] = make_float2(f0, f1);
    }
}

// ---------------- launcher ----------------
extern "C" void kernel_launch(void* const* d_in, const int* in_sizes, int n_in,
                              void* d_out, int out_size, void* d_ws, size_t ws_size,
                              hipStream_t stream) {
    const float* inp     = (const float*)d_in[0];   // (1,128,17400) fp32
    const int*   indices = (const int*)d_in[1];     // (800000,2)
    const float* weights = (const float*)d_in[2];   // (800000,)
    const float* sw      = (const float*)d_in[3];   // (10,5)
    const int*   syn     = (const int*)d_in[4];     // (800000,)

    char* ws = (char*)d_ws;
    __hip_bfloat162* xTb = (__hip_bfloat162*)(ws);          // 17400*64*4 = 4,454,400 B
    int* counts          = (int*)(ws + 4454400);            // 200,000 B

    const size_t ELL_BYTES_END = 4654400ULL + (size_t)N_POST * ELL_CAP * 8;  // 23,854,400
    bool useEll = (ws_size >= ELL_BYTES_END);

    if (useEll) {
        int2* ell = (int2*)(ws + 4654400);                  // 19,200,000 B
        hipMemsetAsync(counts, 0, 200000, stream);
        k_prep<<<SCAT_BLOCKS + TPOSE_BLOCKS, 256, 0, stream>>>(
            inp, xTb, (const int4*)indices, (const float4*)weights, (const int4*)syn,
            counts, ell);
        k_compute<<<N_POST / 8, 512, 0, stream>>>(xTb, ell, nullptr, counts, sw,
                                                  (float2*)d_out, ELL_CAP, 1);
    } else {
        int* cursor    = (int*)(ws + 4654400);              // 200,000 B (adjacent to counts)
        int* rowStart  = (int*)(ws + 4854400);              // 200,000 B
        int* blockSums = (int*)(ws + 5054400);              // 256 B
        int* blockOffs = (int*)(ws + 5054656);              // 256 B
        int2* edges    = (int2*)(ws + 5054912);             // 6,400,000 B
        hipMemsetAsync(counts, 0, 400000, stream);          // counts + cursor
        k_transpose_bf16<<<(N_LGN + 63) / 64, 256, 0, stream>>>(inp, xTb);
        k_hist<<<(NNZ / 2 + 255) / 256, 256, 0, stream>>>((const int4*)indices, counts);
        k_scan1<<<(N_POST + 1023) / 1024, 1024, 0, stream>>>(counts, rowStart, blockSums);
        k_scan2<<<1, 64, 0, stream>>>(blockSums, blockOffs, (N_POST + 1023) / 1024);
        k_scan3<<<(N_POST + 1023) / 1024, 1024, 0, stream>>>(rowStart, blockOffs);
        k_scatter_csr<<<(NNZ / 2 + 255) / 256, 256, 0, stream>>>(
            (const int4*)indices, (const float2*)weights, (const int2*)syn,
            rowStart, cursor, edges);
        k_compute<<<N_POST / 8, 512, 0, stream>>>(xTb, edges, rowStart, counts, sw,
                                                  (float2*)d_out, 1 << 30, 0);
    }
}

// Round 3
// 267.137 us; speedup vs baseline: 1.9724x; 1.9724x over previous
//
#include <hip/hip_runtime.h>
#include <hip/hip_bf16.h>
#include <stdint.h>

#define N_LGN   17400
#define N_POST  50000
#define NNZ     800000
#define N_BASIS 5
#define ELL_CAP 48

#define TPOSE_CBLK   32
#define TPOSE_BLOCKS ((N_LGN + TPOSE_CBLK - 1) / TPOSE_CBLK)   // 544
#define SCAT_THREADS (NNZ / 4)                                  // 200000 (4 edges/thread)
#define SCAT_BLOCKS  ((SCAT_THREADS + 255) / 256)               // 782

// ---------------- fused prep: scatter (blocks [0,782)) + transpose (blocks [782,1326)) ----
__global__ __launch_bounds__(256) void k_prep(const float* __restrict__ inp,
                                              __hip_bfloat162* __restrict__ xTb,
                                              const int4* __restrict__ idx4,
                                              const float4* __restrict__ w4,
                                              const int4* __restrict__ syn4,
                                              int* __restrict__ counts,
                                              int2* __restrict__ ell) {
    __shared__ float tile[TPOSE_CBLK * 129];
    int tid = threadIdx.x;
    if (blockIdx.x < SCAT_BLOCKS) {
        int t = blockIdx.x * 256 + tid;
        if (t >= SCAT_THREADS) return;
        int4 iA = idx4[2 * t];          // edges 4t,4t+1: (row,col,row,col)
        int4 iB = idx4[2 * t + 1];      // edges 4t+2,4t+3
        float4 ww = w4[t];
        int4 sy = syn4[t];
        int r0 = atomicAdd(&counts[iA.x], 1);
        if (r0 < ELL_CAP) ell[iA.x * ELL_CAP + r0] = make_int2(iA.y | (sy.x << 16), __float_as_int(ww.x));
        int r1 = atomicAdd(&counts[iA.z], 1);
        if (r1 < ELL_CAP) ell[iA.z * ELL_CAP + r1] = make_int2(iA.w | (sy.y << 16), __float_as_int(ww.y));
        int r2 = atomicAdd(&counts[iB.x], 1);
        if (r2 < ELL_CAP) ell[iB.x * ELL_CAP + r2] = make_int2(iB.y | (sy.z << 16), __float_as_int(ww.z));
        int r3 = atomicAdd(&counts[iB.z], 1);
        if (r3 < ELL_CAP) ell[iB.z * ELL_CAP + r3] = make_int2(iB.w | (sy.w << 16), __float_as_int(ww.w));
    } else {
        int c0 = (blockIdx.x - SCAT_BLOCKS) * TPOSE_CBLK;
        for (int it = 0; it < 16; ++it) {
            int flat = it * 256 + tid;
            int s  = flat >> 5;
            int cl = flat & 31;
            int c  = c0 + cl;
            float v = 0.0f;
            if (c < N_LGN) v = inp[s * N_LGN + c];
            tile[cl * 129 + s] = v;
        }
        __syncthreads();
        for (int it = 0; it < 8; ++it) {
            int flat = it * 256 + tid;
            int cl = flat >> 6;
            int sp = flat & 63;
            int c  = c0 + cl;
            if (c < N_LGN) {
                float2 f = make_float2(tile[cl * 129 + 2 * sp], tile[cl * 129 + 2 * sp + 1]);
                xTb[c * 64 + sp] = __float22bfloat162_rn(f);
            }
        }
    }
}

// ---------------- CSR fallback path (used only if ws too small for ELL) ----------------
__global__ __launch_bounds__(256) void k_transpose_bf16(const float* __restrict__ inp,
                                                        __hip_bfloat162* __restrict__ xTb) {
    __shared__ float tile[64 * 129];
    int c0  = blockIdx.x * 64;
    int tid = threadIdx.x;
    for (int it = 0; it < 32; ++it) {
        int flat = it * 256 + tid;
        int s  = flat >> 6;
        int cl = flat & 63;
        int c  = c0 + cl;
        float v = 0.0f;
        if (c < N_LGN) v = inp[s * N_LGN + c];
        tile[cl * 129 + s] = v;
    }
    __syncthreads();
    for (int it = 0; it < 16; ++it) {
        int flat = it * 256 + tid;
        int cl = flat >> 6;
        int sp = flat & 63;
        int c  = c0 + cl;
        if (c < N_LGN) {
            float2 f = make_float2(tile[cl * 129 + 2 * sp], tile[cl * 129 + 2 * sp + 1]);
            xTb[c * 64 + sp] = __float22bfloat162_rn(f);
        }
    }
}

__global__ __launch_bounds__(256) void k_hist(const int4* __restrict__ idx2,
                                              int* __restrict__ counts) {
    int t = blockIdx.x * 256 + threadIdx.x;
    if (t >= NNZ / 2) return;
    int4 rc = idx2[t];
    atomicAdd(&counts[rc.x], 1);
    atomicAdd(&counts[rc.z], 1);
}

__global__ __launch_bounds__(1024) void k_scan1(const int* __restrict__ counts,
                                                int* __restrict__ rowStart,
                                                int* __restrict__ blockSums) {
    __shared__ int tmp[1024];
    int tid = threadIdx.x;
    int gid = blockIdx.x * 1024 + tid;
    int v = (gid < N_POST) ? counts[gid] : 0;
    tmp[tid] = v;
    __syncthreads();
    for (int off = 1; off < 1024; off <<= 1) {
        int t = (tid >= off) ? tmp[tid - off] : 0;
        __syncthreads();
        tmp[tid] += t;
        __syncthreads();
    }
    if (gid < N_POST) rowStart[gid] = tmp[tid] - v;
    if (tid == 1023) blockSums[blockIdx.x] = tmp[1023];
}

__global__ __launch_bounds__(64) void k_scan2(const int* __restrict__ blockSums,
                                              int* __restrict__ blockOffsets, int nblk) {
    __shared__ int tmp[64];
    int tid = threadIdx.x;
    int v = (tid < nblk) ? blockSums[tid] : 0;
    tmp[tid] = v;
    __syncthreads();
    for (int off = 1; off < 64; off <<= 1) {
        int t = (tid >= off) ? tmp[tid - off] : 0;
        __syncthreads();
        tmp[tid] += t;
        __syncthreads();
    }
    if (tid < nblk) blockOffsets[tid] = tmp[tid] - v;
}

__global__ __launch_bounds__(1024) void k_scan3(int* __restrict__ rowStart,
                                                const int* __restrict__ blockOffsets) {
    int gid = blockIdx.x * 1024 + threadIdx.x;
    if (gid < N_POST) rowStart[gid] += blockOffsets[blockIdx.x];
}

__global__ __launch_bounds__(256) void k_scatter_csr(const int4* __restrict__ idx2,
                                                     const float2* __restrict__ w2,
                                                     const int2* __restrict__ syn2,
                                                     const int* __restrict__ rowStart,
                                                     int* __restrict__ cursor,
                                                     int2* __restrict__ edges) {
    int t = blockIdx.x * 256 + threadIdx.x;
    if (t >= NNZ / 2) return;
    int4 rc = idx2[t];
    float2 ww = w2[t];
    int2 sy = syn2[t];
    int p0 = rowStart[rc.x] + atomicAdd(&cursor[rc.x], 1);
    edges[p0] = make_int2(rc.y | (sy.x << 16), __float_as_int(ww.x));
    int p1 = rowStart[rc.z] + atomicAdd(&cursor[rc.z], 1);
    edges[p1] = make_int2(rc.w | (sy.y << 16), __float_as_int(ww.y));
}

// per-edge FMA body: x scaled by w, 5 basis factors from padded facs
#define EDGE_FMA(XW, FA, F4)                                          \
    a0[0] = fmaf((XW).x, (FA).x, a0[0]); a1[0] = fmaf((XW).y, (FA).x, a1[0]); \
    a0[1] = fmaf((XW).x, (FA).y, a0[1]); a1[1] = fmaf((XW).y, (FA).y, a1[1]); \
    a0[2] = fmaf((XW).x, (FA).z, a0[2]); a1[2] = fmaf((XW).y, (FA).z, a1[2]); \
    a0[3] = fmaf((XW).x, (FA).w, a0[3]); a1[3] = fmaf((XW).y, (FA).w, a1[3]); \
    a0[4] = fmaf((XW).x, (F4),   a0[4]); a1[4] = fmaf((XW).y, (F4),   a1[4]);

// ---------------- main compute: one wave per row, edges staged in LDS --------------------
// The gather's critical path in earlier versions was: global 8B edge load (~300cy, wave-
// uniform) -> dependent 256B gather (~300cy). The block's entire ELL slab is only 3KB, so
// stage it with one coalesced 3072B burst; the loop's only global op is then the gather
// itself (4 independent in flight per wave).
__global__ __launch_bounds__(512, 8) void k_compute(const __hip_bfloat162* __restrict__ xTb,
                                                    const int2* __restrict__ edges,
                                                    const int* __restrict__ rowStart,
                                                    const int* __restrict__ counts,
                                                    const float* __restrict__ sw,
                                                    float2* __restrict__ out2,
                                                    int cap, int useEll) {
    __shared__ alignas(16) float facsP[80];        // synaptic_weights 10x5, padded to 10x8
    __shared__ float accLds[40 * 133];             // [j = wave*5+r][s], pitch 133
    __shared__ alignas(16) int2 eLds[8 * ELL_CAP]; // this block's ELL slab (3072B)
    int tid  = threadIdx.x;
    int wave = tid >> 6;
    int lane = tid & 63;
    int n    = blockIdx.x * 8 + wave;              // 6250*8 == 50000 exactly
    int cnt  = counts[n];
    if (cnt > cap) cnt = cap;

    if (tid < 50) facsP[(tid / 5) * 8 + (tid % 5)] = sw[tid];
    if (useEll && tid < 8 * ELL_CAP / 2) {         // 192 threads x int4 = 3072B coalesced
        ((int4*)eLds)[tid] =
            ((const int4*)(edges + (size_t)blockIdx.x * (8 * ELL_CAP)))[tid];
    }
    __syncthreads();

    float a0[N_BASIS] = {0.f, 0.f, 0.f, 0.f, 0.f};
    float a1[N_BASIS] = {0.f, 0.f, 0.f, 0.f, 0.f};

    if (useEll) {
        const int4* ep4 = (const int4*)(eLds + wave * ELL_CAP);  // 48*8B: 16B aligned
        int j = 0;
        for (; j + 3 < cnt; j += 4) {
            int4 E0 = ep4[(j >> 1)];
            int4 E1 = ep4[(j >> 1) + 1];
            int c0 = E0.x & 0xFFFF, sy0 = E0.x >> 16; float w0 = __int_as_float(E0.y);
            int c1 = E0.z & 0xFFFF, sy1 = E0.z >> 16; float w1 = __int_as_float(E0.w);
            int c2 = E1.x & 0xFFFF, sy2 = E1.x >> 16; float w2 = __int_as_float(E1.y);
            int c3 = E1.z & 0xFFFF, sy3 = E1.z >> 16; float w3 = __int_as_float(E1.w);
            float2 x0 = __bfloat1622float2(xTb[c0 * 64 + lane]);   // 4 gathers in flight
            float2 x1 = __bfloat1622float2(xTb[c1 * 64 + lane]);
            float2 x2 = __bfloat1622float2(xTb[c2 * 64 + lane]);
            float2 x3 = __bfloat1622float2(xTb[c3 * 64 + lane]);
            float4 fA0 = *(const float4*)&facsP[sy0 * 8]; float f40 = facsP[sy0 * 8 + 4];
            float4 fA1 = *(const float4*)&facsP[sy1 * 8]; float f41 = facsP[sy1 * 8 + 4];
            float4 fA2 = *(const float4*)&facsP[sy2 * 8]; float f42 = facsP[sy2 * 8 + 4];
            float4 fA3 = *(const float4*)&facsP[sy3 * 8]; float f43 = facsP[sy3 * 8 + 4];
            float2 xw0 = make_float2(x0.x * w0, x0.y * w0);
            float2 xw1 = make_float2(x1.x * w1, x1.y * w1);
            float2 xw2 = make_float2(x2.x * w2, x2.y * w2);
            float2 xw3 = make_float2(x3.x * w3, x3.y * w3);
            EDGE_FMA(xw0, fA0, f40)
            EDGE_FMA(xw1, fA1, f41)
            EDGE_FMA(xw2, fA2, f42)
            EDGE_FMA(xw3, fA3, f43)
        }
        for (; j < cnt; ++j) {
            int2 e = eLds[wave * ELL_CAP + j];
            int c = e.x & 0xFFFF, sy = e.x >> 16;
            float w = __int_as_float(e.y);
            float2 x = __bfloat1622float2(xTb[c * 64 + lane]);
            float4 fA = *(const float4*)&facsP[sy * 8]; float f4 = facsP[sy * 8 + 4];
            float2 xw = make_float2(x.x * w, x.y * w);
            EDGE_FMA(xw, fA, f4)
        }
    } else {
        // CSR fallback: edges read directly from global (safety path)
        const int2* ep = edges + rowStart[n];
        int j = 0;
        for (; j + 1 < cnt; j += 2) {
            int2 e0 = ep[j];
            int2 e1 = ep[j + 1];
            int c0 = e0.x & 0xFFFF, sy0 = e0.x >> 16;
            int c1 = e1.x & 0xFFFF, sy1 = e1.x >> 16;
            float2 x0 = __bfloat1622float2(xTb[c0 * 64 + lane]);
            float2 x1 = __bfloat1622float2(xTb[c1 * 64 + lane]);
            float w0 = __int_as_float(e0.y);
            float w1 = __int_as_float(e1.y);
            float4 fA0 = *(const float4*)&facsP[sy0 * 8]; float f40 = facsP[sy0 * 8 + 4];
            float4 fA1 = *(const float4*)&facsP[sy1 * 8]; float f41 = facsP[sy1 * 8 + 4];
            float2 xw0 = make_float2(x0.x * w0, x0.y * w0);
            float2 xw1 = make_float2(x1.x * w1, x1.y * w1);
            EDGE_FMA(xw0, fA0, f40)
            EDGE_FMA(xw1, fA1, f41)
        }
        if (j < cnt) {
            int2 e0 = ep[j];
            int c0 = e0.x & 0xFFFF, sy0 = e0.x >> 16;
            float2 x0 = __bfloat1622float2(xTb[c0 * 64 + lane]);
            float w0 = __int_as_float(e0.y);
            float4 fA0 = *(const float4*)&facsP[sy0 * 8]; float f40 = facsP[sy0 * 8 + 4];
            float2 xw0 = make_float2(x0.x * w0, x0.y * w0);
            EDGE_FMA(xw0, fA0, f40)
        }
    }

#pragma unroll
    for (int r = 0; r < N_BASIS; ++r) {
        int jj = wave * 5 + r;
        accLds[jj * 133 + 2 * lane]     = a0[r];   // s = 2*lane
        accLds[jj * 133 + 2 * lane + 1] = a1[r];   // s = 2*lane+1
    }
    __syncthreads();

    // epilogue: 128 s x 40 floats = 2560 float2; contiguous 160B runs per s
    int base2 = blockIdx.x * 20;
    for (int it = 0; it < 5; ++it) {
        int flat = it * 512 + tid;          // 0..2559
        int s  = flat / 20;
        int jj = flat % 20;
        float f0 = accLds[(2 * jj) * 133 + s];
        float f1 = accLds[(2 * jj + 1) * 133 + s];
        out2[s * 125000 + base2 + jj] = make_float2(f0, f1);
    }
}

// ---------------- launcher ----------------
extern "C" void kernel_launch(void* const* d_in, const int* in_sizes, int n_in,
                              void* d_out, int out_size, void* d_ws, size_t ws_size,
                              hipStream_t stream) {
    const float* inp     = (const float*)d_in[0];   // (1,128,17400) fp32
    const int*   indices = (const int*)d_in[1];     // (800000,2)
    const float* weights = (const float*)d_in[2];   // (800000,)
    const float* sw      = (const float*)d_in[3];   // (10,5)
    const int*   syn     = (const int*)d_in[4];     // (800000,)

    char* ws = (char*)d_ws;
    __hip_bfloat162* xTb = (__hip_bfloat162*)(ws);          // 17400*64*4 = 4,454,400 B
    int* counts          = (int*)(ws + 4454400);            // 200,000 B

    const size_t ELL_BYTES_END = 4654400ULL + (size_t)N_POST * ELL_CAP * 8;  // 23,854,400
    bool useEll = (ws_size >= ELL_BYTES_END);

    if (useEll) {
        int2* ell = (int2*)(ws + 4654400);                  // 19,200,000 B (16B aligned)
        hipMemsetAsync(counts, 0, 200000, stream);
        k_prep<<<SCAT_BLOCKS + TPOSE_BLOCKS, 256, 0, stream>>>(
            inp, xTb, (const int4*)indices, (const float4*)weights, (const int4*)syn,
            counts, ell);
        k_compute<<<N_POST / 8, 512, 0, stream>>>(xTb, ell, nullptr, counts, sw,
                                                  (float2*)d_out, ELL_CAP, 1);
    } else {
        int* cursor    = (int*)(ws + 4654400);              // 200,000 B (adjacent to counts)
        int* rowStart  = (int*)(ws + 4854400);              // 200,000 B
        int* blockSums = (int*)(ws + 5054400);              // 256 B
        int* blockOffs = (int*)(ws + 5054656);              // 256 B
        int2* edges    = (int2*)(ws + 5054912);             // 6,400,000 B
        hipMemsetAsync(counts, 0, 400000, stream);          // counts + cursor
        k_transpose_bf16<<<(N_LGN + 63) / 64, 256, 0, stream>>>(inp, xTb);
        k_hist<<<(NNZ / 2 + 255) / 256, 256, 0, stream>>>((const int4*)indices, counts);
        k_scan1<<<(N_POST + 1023) / 1024, 1024, 0, stream>>>(counts, rowStart, blockSums);
        k_scan2<<<1, 64, 0, stream>>>(blockSums, blockOffs, (N_POST + 1023) / 1024);
        k_scan3<<<(N_POST + 1023) / 1024, 1024, 0, stream>>>(rowStart, blockOffs);
        k_scatter_csr<<<(NNZ / 2 + 255) / 256, 256, 0, stream>>>(
            (const int4*)indices, (const float2*)weights, (const int2*)syn,
            rowStart, cursor, edges);
        k_compute<<<N_POST / 8, 512, 0, stream>>>(xTb, edges, rowStart, counts, sw,
                                                  (float2*)d_out, 1 << 30, 0);
    }
}

// Round 4
// 264.298 us; speedup vs baseline: 1.9936x; 1.0107x over previous
//
#include <hip/hip_runtime.h>
#include <hip/hip_bf16.h>
#include <stdint.h>

#define N_LGN   17400
#define N_POST  50000
#define NNZ     800000
#define N_BASIS 5
#define ELL_CAP 48

#define TPOSE_CBLK   32
#define TPOSE_BLOCKS ((N_LGN + TPOSE_CBLK - 1) / TPOSE_CBLK)   // 544
#define SCAT_THREADS (NNZ / 4)                                  // 200000 (4 edges/thread)
#define SCAT_BLOCKS  ((SCAT_THREADS + 255) / 256)               // 782

// ---------------- fused prep: scatter (blocks [0,782)) + transpose (blocks [782,1326)) ----
__global__ __launch_bounds__(256) void k_prep(const float* __restrict__ inp,
                                              __hip_bfloat162* __restrict__ xTb,
                                              const int4* __restrict__ idx4,
                                              const float4* __restrict__ w4,
                                              const int4* __restrict__ syn4,
                                              int* __restrict__ counts,
                                              int2* __restrict__ ell) {
    __shared__ float tile[TPOSE_CBLK * 129];
    int tid = threadIdx.x;
    if (blockIdx.x < SCAT_BLOCKS) {
        int t = blockIdx.x * 256 + tid;
        if (t >= SCAT_THREADS) return;
        int4 iA = idx4[2 * t];          // edges 4t,4t+1: (row,col,row,col)
        int4 iB = idx4[2 * t + 1];      // edges 4t+2,4t+3
        float4 ww = w4[t];
        int4 sy = syn4[t];
        // Issue all 4 atomics BEFORE any dependent store: the 4 device-scope round
        // trips overlap instead of serializing (was 4 x ~2k cycles serial per wave).
        int r0 = atomicAdd(&counts[iA.x], 1);
        int r1 = atomicAdd(&counts[iA.z], 1);
        int r2 = atomicAdd(&counts[iB.x], 1);
        int r3 = atomicAdd(&counts[iB.z], 1);
        if (r0 < ELL_CAP) ell[iA.x * ELL_CAP + r0] = make_int2(iA.y | (sy.x << 16), __float_as_int(ww.x));
        if (r1 < ELL_CAP) ell[iA.z * ELL_CAP + r1] = make_int2(iA.w | (sy.y << 16), __float_as_int(ww.y));
        if (r2 < ELL_CAP) ell[iB.x * ELL_CAP + r2] = make_int2(iB.y | (sy.z << 16), __float_as_int(ww.z));
        if (r3 < ELL_CAP) ell[iB.z * ELL_CAP + r3] = make_int2(iB.w | (sy.w << 16), __float_as_int(ww.w));
    } else {
        int c0 = (blockIdx.x - SCAT_BLOCKS) * TPOSE_CBLK;
        for (int it = 0; it < 16; ++it) {
            int flat = it * 256 + tid;
            int s  = flat >> 5;
            int cl = flat & 31;
            int c  = c0 + cl;
            float v = 0.0f;
            if (c < N_LGN) v = inp[s * N_LGN + c];
            tile[cl * 129 + s] = v;
        }
        __syncthreads();
        for (int it = 0; it < 8; ++it) {
            int flat = it * 256 + tid;
            int cl = flat >> 6;
            int sp = flat & 63;
            int c  = c0 + cl;
            if (c < N_LGN) {
                float2 f = make_float2(tile[cl * 129 + 2 * sp], tile[cl * 129 + 2 * sp + 1]);
                xTb[c * 64 + sp] = __float22bfloat162_rn(f);
            }
        }
    }
}

// ---------------- CSR fallback path (used only if ws too small for ELL) ----------------
__global__ __launch_bounds__(256) void k_transpose_bf16(const float* __restrict__ inp,
                                                        __hip_bfloat162* __restrict__ xTb) {
    __shared__ float tile[64 * 129];
    int c0  = blockIdx.x * 64;
    int tid = threadIdx.x;
    for (int it = 0; it < 32; ++it) {
        int flat = it * 256 + tid;
        int s  = flat >> 6;
        int cl = flat & 63;
        int c  = c0 + cl;
        float v = 0.0f;
        if (c < N_LGN) v = inp[s * N_LGN + c];
        tile[cl * 129 + s] = v;
    }
    __syncthreads();
    for (int it = 0; it < 16; ++it) {
        int flat = it * 256 + tid;
        int cl = flat >> 6;
        int sp = flat & 63;
        int c  = c0 + cl;
        if (c < N_LGN) {
            float2 f = make_float2(tile[cl * 129 + 2 * sp], tile[cl * 129 + 2 * sp + 1]);
            xTb[c * 64 + sp] = __float22bfloat162_rn(f);
        }
    }
}

__global__ __launch_bounds__(256) void k_hist(const int4* __restrict__ idx2,
                                              int* __restrict__ counts) {
    int t = blockIdx.x * 256 + threadIdx.x;
    if (t >= NNZ / 2) return;
    int4 rc = idx2[t];
    atomicAdd(&counts[rc.x], 1);
    atomicAdd(&counts[rc.z], 1);
}

__global__ __launch_bounds__(1024) void k_scan1(const int* __restrict__ counts,
                                                int* __restrict__ rowStart,
                                                int* __restrict__ blockSums) {
    __shared__ int tmp[1024];
    int tid = threadIdx.x;
    int gid = blockIdx.x * 1024 + tid;
    int v = (gid < N_POST) ? counts[gid] : 0;
    tmp[tid] = v;
    __syncthreads();
    for (int off = 1; off < 1024; off <<= 1) {
        int t = (tid >= off) ? tmp[tid - off] : 0;
        __syncthreads();
        tmp[tid] += t;
        __syncthreads();
    }
    if (gid < N_POST) rowStart[gid] = tmp[tid] - v;
    if (tid == 1023) blockSums[blockIdx.x] = tmp[1023];
}

__global__ __launch_bounds__(64) void k_scan2(const int* __restrict__ blockSums,
                                              int* __restrict__ blockOffsets, int nblk) {
    __shared__ int tmp[64];
    int tid = threadIdx.x;
    int v = (tid < nblk) ? blockSums[tid] : 0;
    tmp[tid] = v;
    __syncthreads();
    for (int off = 1; off < 64; off <<= 1) {
        int t = (tid >= off) ? tmp[tid - off] : 0;
        __syncthreads();
        tmp[tid] += t;
        __syncthreads();
    }
    if (tid < nblk) blockOffsets[tid] = tmp[tid] - v;
}

__global__ __launch_bounds__(1024) void k_scan3(int* __restrict__ rowStart,
                                                const int* __restrict__ blockOffsets) {
    int gid = blockIdx.x * 1024 + threadIdx.x;
    if (gid < N_POST) rowStart[gid] += blockOffsets[blockIdx.x];
}

__global__ __launch_bounds__(256) void k_scatter_csr(const int4* __restrict__ idx2,
                                                     const float2* __restrict__ w2,
                                                     const int2* __restrict__ syn2,
                                                     const int* __restrict__ rowStart,
                                                     int* __restrict__ cursor,
                                                     int2* __restrict__ edges) {
    int t = blockIdx.x * 256 + threadIdx.x;
    if (t >= NNZ / 2) return;
    int4 rc = idx2[t];
    float2 ww = w2[t];
    int2 sy = syn2[t];
    int p0 = rowStart[rc.x] + atomicAdd(&cursor[rc.x], 1);
    edges[p0] = make_int2(rc.y | (sy.x << 16), __float_as_int(ww.x));
    int p1 = rowStart[rc.z] + atomicAdd(&cursor[rc.z], 1);
    edges[p1] = make_int2(rc.w | (sy.y << 16), __float_as_int(ww.y));
}

// per-edge FMA body: x scaled by w, 5 basis factors from padded facs
#define EDGE_FMA(XW, FA, F4)                                          \
    a0[0] = fmaf((XW).x, (FA).x, a0[0]); a1[0] = fmaf((XW).y, (FA).x, a1[0]); \
    a0[1] = fmaf((XW).x, (FA).y, a0[1]); a1[1] = fmaf((XW).y, (FA).y, a1[1]); \
    a0[2] = fmaf((XW).x, (FA).z, a0[2]); a1[2] = fmaf((XW).y, (FA).z, a1[2]); \
    a0[3] = fmaf((XW).x, (FA).w, a0[3]); a1[3] = fmaf((XW).y, (FA).w, a1[3]); \
    a0[4] = fmaf((XW).x, (F4),   a0[4]); a1[4] = fmaf((XW).y, (F4),   a1[4]);

// ---------------- main compute: one wave per row, edges staged in LDS --------------------
__global__ __launch_bounds__(512, 8) void k_compute(const __hip_bfloat162* __restrict__ xTb,
                                                    const int2* __restrict__ edges,
                                                    const int* __restrict__ rowStart,
                                                    const int* __restrict__ counts,
                                                    const float* __restrict__ sw,
                                                    float2* __restrict__ out2,
                                                    int cap, int useEll) {
    __shared__ alignas(16) float facsP[80];        // synaptic_weights 10x5, padded to 10x8
    __shared__ float accLds[40 * 133];             // [j = wave*5+r][s], pitch 133
    __shared__ alignas(16) int2 eLds[8 * ELL_CAP]; // this block's ELL slab (3072B)
    int tid  = threadIdx.x;
    int wave = tid >> 6;
    int lane = tid & 63;
    int n    = blockIdx.x * 8 + wave;              // 6250*8 == 50000 exactly
    int cnt  = counts[n];
    if (cnt > cap) cnt = cap;

    if (tid < 50) facsP[(tid / 5) * 8 + (tid % 5)] = sw[tid];
    if (useEll && tid < 8 * ELL_CAP / 2) {         // 192 threads x int4 = 3072B coalesced
        ((int4*)eLds)[tid] =
            ((const int4*)(edges + (size_t)blockIdx.x * (8 * ELL_CAP)))[tid];
    }
    __syncthreads();

    float a0[N_BASIS] = {0.f, 0.f, 0.f, 0.f, 0.f};
    float a1[N_BASIS] = {0.f, 0.f, 0.f, 0.f, 0.f};

    if (useEll) {
        const int4* ep4 = (const int4*)(eLds + wave * ELL_CAP);  // 48*8B: 16B aligned
        int j = 0;
        for (; j + 3 < cnt; j += 4) {
            int4 E0 = ep4[(j >> 1)];
            int4 E1 = ep4[(j >> 1) + 1];
            int c0 = E0.x & 0xFFFF, sy0 = E0.x >> 16; float w0 = __int_as_float(E0.y);
            int c1 = E0.z & 0xFFFF, sy1 = E0.z >> 16; float w1 = __int_as_float(E0.w);
            int c2 = E1.x & 0xFFFF, sy2 = E1.x >> 16; float w2 = __int_as_float(E1.y);
            int c3 = E1.z & 0xFFFF, sy3 = E1.z >> 16; float w3 = __int_as_float(E1.w);
            float2 x0 = __bfloat1622float2(xTb[c0 * 64 + lane]);   // 4 gathers in flight
            float2 x1 = __bfloat1622float2(xTb[c1 * 64 + lane]);
            float2 x2 = __bfloat1622float2(xTb[c2 * 64 + lane]);
            float2 x3 = __bfloat1622float2(xTb[c3 * 64 + lane]);
            float4 fA0 = *(const float4*)&facsP[sy0 * 8]; float f40 = facsP[sy0 * 8 + 4];
            float4 fA1 = *(const float4*)&facsP[sy1 * 8]; float f41 = facsP[sy1 * 8 + 4];
            float4 fA2 = *(const float4*)&facsP[sy2 * 8]; float f42 = facsP[sy2 * 8 + 4];
            float4 fA3 = *(const float4*)&facsP[sy3 * 8]; float f43 = facsP[sy3 * 8 + 4];
            float2 xw0 = make_float2(x0.x * w0, x0.y * w0);
            float2 xw1 = make_float2(x1.x * w1, x1.y * w1);
            float2 xw2 = make_float2(x2.x * w2, x2.y * w2);
            float2 xw3 = make_float2(x3.x * w3, x3.y * w3);
            EDGE_FMA(xw0, fA0, f40)
            EDGE_FMA(xw1, fA1, f41)
            EDGE_FMA(xw2, fA2, f42)
            EDGE_FMA(xw3, fA3, f43)
        }
        for (; j < cnt; ++j) {
            int2 e = eLds[wave * ELL_CAP + j];
            int c = e.x & 0xFFFF, sy = e.x >> 16;
            float w = __int_as_float(e.y);
            float2 x = __bfloat1622float2(xTb[c * 64 + lane]);
            float4 fA = *(const float4*)&facsP[sy * 8]; float f4 = facsP[sy * 8 + 4];
            float2 xw = make_float2(x.x * w, x.y * w);
            EDGE_FMA(xw, fA, f4)
        }
    } else {
        // CSR fallback: edges read directly from global (safety path)
        const int2* ep = edges + rowStart[n];
        int j = 0;
        for (; j + 1 < cnt; j += 2) {
            int2 e0 = ep[j];
            int2 e1 = ep[j + 1];
            int c0 = e0.x & 0xFFFF, sy0 = e0.x >> 16;
            int c1 = e1.x & 0xFFFF, sy1 = e1.x >> 16;
            float2 x0 = __bfloat1622float2(xTb[c0 * 64 + lane]);
            float2 x1 = __bfloat1622float2(xTb[c1 * 64 + lane]);
            float w0 = __int_as_float(e0.y);
            float w1 = __int_as_float(e1.y);
            float4 fA0 = *(const float4*)&facsP[sy0 * 8]; float f40 = facsP[sy0 * 8 + 4];
            float4 fA1 = *(const float4*)&facsP[sy1 * 8]; float f41 = facsP[sy1 * 8 + 4];
            float2 xw0 = make_float2(x0.x * w0, x0.y * w0);
            float2 xw1 = make_float2(x1.x * w1, x1.y * w1);
            EDGE_FMA(xw0, fA0, f40)
            EDGE_FMA(xw1, fA1, f41)
        }
        if (j < cnt) {
            int2 e0 = ep[j];
            int c0 = e0.x & 0xFFFF, sy0 = e0.x >> 16;
            float2 x0 = __bfloat1622float2(xTb[c0 * 64 + lane]);
            float w0 = __int_as_float(e0.y);
            float4 fA0 = *(const float4*)&facsP[sy0 * 8]; float f40 = facsP[sy0 * 8 + 4];
            float2 xw0 = make_float2(x0.x * w0, x0.y * w0);
            EDGE_FMA(xw0, fA0, f40)
        }
    }

#pragma unroll
    for (int r = 0; r < N_BASIS; ++r) {
        int jj = wave * 5 + r;
        accLds[jj * 133 + 2 * lane]     = a0[r];   // s = 2*lane
        accLds[jj * 133 + 2 * lane + 1] = a1[r];   // s = 2*lane+1
    }
    __syncthreads();

    // epilogue: 128 s x 40 floats = 2560 float2; contiguous 160B runs per s
    int base2 = blockIdx.x * 20;
    for (int it = 0; it < 5; ++it) {
        int flat = it * 512 + tid;          // 0..2559
        int s  = flat / 20;
        int jj = flat % 20;
        float f0 = accLds[(2 * jj) * 133 + s];
        float f1 = accLds[(2 * jj + 1) * 133 + s];
        out2[s * 125000 + base2 + jj] = make_float2(f0, f1);
    }
}

// ---------------- launcher ----------------
extern "C" void kernel_launch(void* const* d_in, const int* in_sizes, int n_in,
                              void* d_out, int out_size, void* d_ws, size_t ws_size,
                              hipStream_t stream) {
    const float* inp     = (const float*)d_in[0];   // (1,128,17400) fp32
    const int*   indices = (const int*)d_in[1];     // (800000,2)
    const float* weights = (const float*)d_in[2];   // (800000,)
    const float* sw      = (const float*)d_in[3];   // (10,5)
    const int*   syn     = (const int*)d_in[4];     // (800000,)

    char* ws = (char*)d_ws;
    __hip_bfloat162* xTb = (__hip_bfloat162*)(ws);          // 17400*64*4 = 4,454,400 B
    int* counts          = (int*)(ws + 4454400);            // 200,000 B

    const size_t ELL_BYTES_END = 4654400ULL + (size_t)N_POST * ELL_CAP * 8;  // 23,854,400
    bool useEll = (ws_size >= ELL_BYTES_END);

    if (useEll) {
        int2* ell = (int2*)(ws + 4654400);                  // 19,200,000 B (16B aligned)
        hipMemsetAsync(counts, 0, 200000, stream);
        k_prep<<<SCAT_BLOCKS + TPOSE_BLOCKS, 256, 0, stream>>>(
            inp, xTb, (const int4*)indices, (const float4*)weights, (const int4*)syn,
            counts, ell);
        k_compute<<<N_POST / 8, 512, 0, stream>>>(xTb, ell, nullptr, counts, sw,
                                                  (float2*)d_out, ELL_CAP, 1);
    } else {
        int* cursor    = (int*)(ws + 4654400);              // 200,000 B (adjacent to counts)
        int* rowStart  = (int*)(ws + 4854400);              // 200,000 B
        int* blockSums = (int*)(ws + 5054400);              // 256 B
        int* blockOffs = (int*)(ws + 5054656);              // 256 B
        int2* edges    = (int2*)(ws + 5054912);             // 6,400,000 B
        hipMemsetAsync(counts, 0, 400000, stream);          // counts + cursor
        k_transpose_bf16<<<(N_LGN + 63) / 64, 256, 0, stream>>>(inp, xTb);
        k_hist<<<(NNZ / 2 + 255) / 256, 256, 0, stream>>>((const int4*)indices, counts);
        k_scan1<<<(N_POST + 1023) / 1024, 1024, 0, stream>>>(counts, rowStart, blockSums);
        k_scan2<<<1, 64, 0, stream>>>(blockSums, blockOffs, (N_POST + 1023) / 1024);
        k_scan3<<<(N_POST + 1023) / 1024, 1024, 0, stream>>>(rowStart, blockOffs);
        k_scatter_csr<<<(NNZ / 2 + 255) / 256, 256, 0, stream>>>(
            (const int4*)indices, (const float2*)weights, (const int2*)syn,
            rowStart, cursor, edges);
        k_compute<<<N_POST / 8, 512, 0, stream>>>(xTb, edges, rowStart, counts, sw,
                                                  (float2*)d_out, 1 << 30, 0);
    }
}

// Round 5
// 214.675 us; speedup vs baseline: 2.4544x; 1.2312x over previous
//
#include <hip/hip_runtime.h>
#include <hip/hip_bf16.h>
#include <stdint.h>

#define N_LGN   17400
#define N_POST  50000
#define NNZ     800000
#define N_BASIS 5
#define ELL_CAP 48

#define NBKT      196        // row buckets of 256 rows (50000/256 -> 196)
#define CAPB      5120       // per-bucket edge capacity (mean 4082, +16 sigma)
#define BIN_CHUNK 4096
#define BIN_BLOCKS ((NNZ + BIN_CHUNK - 1) / BIN_CHUNK)          // 196

#define TPOSE_CBLK   32
#define TPOSE_BLOCKS ((N_LGN + TPOSE_CBLK - 1) / TPOSE_CBLK)    // 544

// ---------------- fused prep: bin edges (blocks [0,196)) + transpose (blocks [196,740)) --
// The old direct ELL scatter wrote 800K random 8B stores -> 53MB of partial-line HBM
// evictions at ~0.85 TB/s (=80us). Here each block bins 4096 edges in LDS (histogram ->
// prefix -> bucket-grouped buffer), then flushes bucket runs (~21 edges) as CONTIGUOUS
// global writes. Global atomics: 196/block instead of 1/edge.
__global__ __launch_bounds__(256) void k_prep(const float* __restrict__ inp,
                                              __hip_bfloat162* __restrict__ xTb,
                                              const int2* __restrict__ idx2,
                                              const float* __restrict__ w,
                                              const int* __restrict__ syn,
                                              int* __restrict__ bucketCnt,
                                              int2* __restrict__ bEdges) {
    __shared__ alignas(16) int2 ebuf[BIN_CHUNK];       // 32KB (transpose aliases tile here)
    __shared__ unsigned char sbuf[BIN_CHUNK];          // bucket id per buffer slot
    __shared__ int hcnt[256], hstart[256], hcur[256], gbase[256];
    int tid = threadIdx.x;
    if (blockIdx.x < BIN_BLOCKS) {
        int base = blockIdx.x * BIN_CHUNK;
        int ne = NNZ - base; if (ne > BIN_CHUNK) ne = BIN_CHUNK;
        hcnt[tid] = 0;
        __syncthreads();
        int2 pk[16]; int bk[16];
#pragma unroll
        for (int i = 0; i < 16; ++i) {
            int p = i * 256 + tid;
            bk[i] = -1;
            if (p < ne) {
                int2 rc = idx2[base + p];                  // (row, col) coalesced
                float wv = w[base + p];
                int sy = syn[base + p];
                int b  = rc.x >> 8;
                int rl = rc.x & 255;
                pk[i] = make_int2(rc.y | (sy << 15) | (rl << 19), __float_as_int(wv));
                bk[i] = b;
                atomicAdd(&hcnt[b], 1);                    // LDS histogram
            }
        }
        __syncthreads();
        // exclusive prefix over 256 bucket counts (hstart as scan workspace)
        int v = hcnt[tid];
        hstart[tid] = v;
        __syncthreads();
        for (int off = 1; off < 256; off <<= 1) {
            int t = (tid >= off) ? hstart[tid - off] : 0;
            __syncthreads();
            hstart[tid] += t;
            __syncthreads();
        }
        int excl = hstart[tid] - v;
        hstart[tid] = excl;
        hcur[tid]  = excl;
        if (tid < NBKT) gbase[tid] = atomicAdd(&bucketCnt[tid], v);  // one atomic per bucket
        __syncthreads();
#pragma unroll
        for (int i = 0; i < 16; ++i) {
            if (bk[i] >= 0) {
                int pos = atomicAdd(&hcur[bk[i]], 1);      // place, grouped by bucket
                ebuf[pos] = pk[i];
                sbuf[pos] = (unsigned char)bk[i];
            }
        }
        __syncthreads();
        for (int p = tid; p < ne; p += 256) {              // flush: contiguous runs per bucket
            int b  = sbuf[p];
            int gi = gbase[b] + (p - hstart[b]);
            if (gi < CAPB) bEdges[b * CAPB + gi] = ebuf[p];
        }
    } else {
        // ---- transpose x (128 x 17400) fp32 -> xTb (17400 x 64) bf16x2, 32-col tiles ----
        float* tile = (float*)ebuf;                        // 32*129*4 = 16,512B <= 32KB
        int c0 = (blockIdx.x - BIN_BLOCKS) * TPOSE_CBLK;
        for (int it = 0; it < 16; ++it) {
            int flat = it * 256 + tid;
            int s  = flat >> 5;
            int cl = flat & 31;
            int c  = c0 + cl;
            float v = 0.0f;
            if (c < N_LGN) v = inp[s * N_LGN + c];
            tile[cl * 129 + s] = v;
        }
        __syncthreads();
        for (int it = 0; it < 8; ++it) {
            int flat = it * 256 + tid;
            int cl = flat >> 6;
            int sp = flat & 63;
            int c  = c0 + cl;
            if (c < N_LGN) {
                float2 f = make_float2(tile[cl * 129 + 2 * sp], tile[cl * 129 + 2 * sp + 1]);
                xTb[c * 64 + sp] = __float22bfloat162_rn(f);
            }
        }
    }
}

// ---------------- build ELL from binned edges: all writes full-line coalesced ------------
__global__ __launch_bounds__(512) void k_build(const int2* __restrict__ bEdges,
                                               const int* __restrict__ bucketCnt,
                                               int2* __restrict__ ell,
                                               int* __restrict__ counts) {
    __shared__ alignas(16) int2 slab[256 * ELL_CAP];   // 98,304B: 256 rows x 48 slots
    __shared__ int rcnt[256];
    int tid = threadIdx.x;
    int b   = blockIdx.x;
    if (tid < 256) rcnt[tid] = 0;
    __syncthreads();
    int cnt = bucketCnt[b]; if (cnt > CAPB) cnt = CAPB;
    for (int p = tid; p < cnt; p += 512) {
        int2 e = bEdges[b * CAPB + p];                 // coalesced read
        int rl = (e.x >> 19) & 0xFF;
        int r = atomicAdd(&rcnt[rl], 1);               // LDS atomic: cheap
        if (r < ELL_CAP)
            slab[rl * ELL_CAP + r] =
                make_int2((e.x & 0x7FFF) | (((e.x >> 15) & 0xF) << 16), e.y);
    }
    __syncthreads();
    const int4* s4 = (const int4*)slab;                // slab -> global, full lines
    int4* e4 = (int4*)(ell + (size_t)b * (256 * ELL_CAP));
    for (int i = tid; i < 256 * ELL_CAP / 2; i += 512) e4[i] = s4[i];
    if (tid < 256) {
        int row = b * 256 + tid;
        if (row < N_POST) counts[row] = rcnt[tid];     // garbage slots never read: clamped
    }
}

// ---------------- CSR fallback path (used only if ws too small for ELL) ----------------
__global__ __launch_bounds__(256) void k_transpose_bf16(const float* __restrict__ inp,
                                                        __hip_bfloat162* __restrict__ xTb) {
    __shared__ float tile[64 * 129];
    int c0  = blockIdx.x * 64;
    int tid = threadIdx.x;
    for (int it = 0; it < 32; ++it) {
        int flat = it * 256 + tid;
        int s  = flat >> 6;
        int cl = flat & 63;
        int c  = c0 + cl;
        float v = 0.0f;
        if (c < N_LGN) v = inp[s * N_LGN + c];
        tile[cl * 129 + s] = v;
    }
    __syncthreads();
    for (int it = 0; it < 16; ++it) {
        int flat = it * 256 + tid;
        int cl = flat >> 6;
        int sp = flat & 63;
        int c  = c0 + cl;
        if (c < N_LGN) {
            float2 f = make_float2(tile[cl * 129 + 2 * sp], tile[cl * 129 + 2 * sp + 1]);
            xTb[c * 64 + sp] = __float22bfloat162_rn(f);
        }
    }
}

__global__ __launch_bounds__(256) void k_hist(const int4* __restrict__ idx2,
                                              int* __restrict__ counts) {
    int t = blockIdx.x * 256 + threadIdx.x;
    if (t >= NNZ / 2) return;
    int4 rc = idx2[t];
    atomicAdd(&counts[rc.x], 1);
    atomicAdd(&counts[rc.z], 1);
}

__global__ __launch_bounds__(1024) void k_scan1(const int* __restrict__ counts,
                                                int* __restrict__ rowStart,
                                                int* __restrict__ blockSums) {
    __shared__ int tmp[1024];
    int tid = threadIdx.x;
    int gid = blockIdx.x * 1024 + tid;
    int v = (gid < N_POST) ? counts[gid] : 0;
    tmp[tid] = v;
    __syncthreads();
    for (int off = 1; off < 1024; off <<= 1) {
        int t = (tid >= off) ? tmp[tid - off] : 0;
        __syncthreads();
        tmp[tid] += t;
        __syncthreads();
    }
    if (gid < N_POST) rowStart[gid] = tmp[tid] - v;
    if (tid == 1023) blockSums[blockIdx.x] = tmp[1023];
}

__global__ __launch_bounds__(64) void k_scan2(const int* __restrict__ blockSums,
                                              int* __restrict__ blockOffsets, int nblk) {
    __shared__ int tmp[64];
    int tid = threadIdx.x;
    int v = (tid < nblk) ? blockSums[tid] : 0;
    tmp[tid] = v;
    __syncthreads();
    for (int off = 1; off < 64; off <<= 1) {
        int t = (tid >= off) ? tmp[tid - off] : 0;
        __syncthreads();
        tmp[tid] += t;
        __syncthreads();
    }
    if (tid < nblk) blockOffsets[tid] = tmp[tid] - v;
}

__global__ __launch_bounds__(1024) void k_scan3(int* __restrict__ rowStart,
                                                const int* __restrict__ blockOffsets) {
    int gid = blockIdx.x * 1024 + threadIdx.x;
    if (gid < N_POST) rowStart[gid] += blockOffsets[blockIdx.x];
}

__global__ __launch_bounds__(256) void k_scatter_csr(const int4* __restrict__ idx2,
                                                     const float2* __restrict__ w2,
                                                     const int2* __restrict__ syn2,
                                                     const int* __restrict__ rowStart,
                                                     int* __restrict__ cursor,
                                                     int2* __restrict__ edges) {
    int t = blockIdx.x * 256 + threadIdx.x;
    if (t >= NNZ / 2) return;
    int4 rc = idx2[t];
    float2 ww = w2[t];
    int2 sy = syn2[t];
    int p0 = rowStart[rc.x] + atomicAdd(&cursor[rc.x], 1);
    edges[p0] = make_int2(rc.y | (sy.x << 16), __float_as_int(ww.x));
    int p1 = rowStart[rc.z] + atomicAdd(&cursor[rc.z], 1);
    edges[p1] = make_int2(rc.w | (sy.y << 16), __float_as_int(ww.y));
}

// per-edge FMA body: x scaled by w, 5 basis factors from padded facs
#define EDGE_FMA(XW, FA, F4)                                          \
    a0[0] = fmaf((XW).x, (FA).x, a0[0]); a1[0] = fmaf((XW).y, (FA).x, a1[0]); \
    a0[1] = fmaf((XW).x, (FA).y, a0[1]); a1[1] = fmaf((XW).y, (FA).y, a1[1]); \
    a0[2] = fmaf((XW).x, (FA).z, a0[2]); a1[2] = fmaf((XW).y, (FA).z, a1[2]); \
    a0[3] = fmaf((XW).x, (FA).w, a0[3]); a1[3] = fmaf((XW).y, (FA).w, a1[3]); \
    a0[4] = fmaf((XW).x, (F4),   a0[4]); a1[4] = fmaf((XW).y, (F4),   a1[4]);

// ---------------- main compute: one wave per row, edges staged in LDS (proven) -----------
__global__ __launch_bounds__(512, 8) void k_compute(const __hip_bfloat162* __restrict__ xTb,
                                                    const int2* __restrict__ edges,
                                                    const int* __restrict__ rowStart,
                                                    const int* __restrict__ counts,
                                                    const float* __restrict__ sw,
                                                    float2* __restrict__ out2,
                                                    int cap, int useEll) {
    __shared__ alignas(16) float facsP[80];        // synaptic_weights 10x5, padded to 10x8
    __shared__ float accLds[40 * 133];             // [j = wave*5+r][s], pitch 133
    __shared__ alignas(16) int2 eLds[8 * ELL_CAP]; // this block's ELL slab (3072B)
    int tid  = threadIdx.x;
    int wave = tid >> 6;
    int lane = tid & 63;
    int n    = blockIdx.x * 8 + wave;              // 6250*8 == 50000 exactly
    int cnt  = counts[n];
    if (cnt > cap) cnt = cap;

    if (tid < 50) facsP[(tid / 5) * 8 + (tid % 5)] = sw[tid];
    if (useEll && tid < 8 * ELL_CAP / 2) {         // 192 threads x int4 = 3072B coalesced
        ((int4*)eLds)[tid] =
            ((const int4*)(edges + (size_t)blockIdx.x * (8 * ELL_CAP)))[tid];
    }
    __syncthreads();

    float a0[N_BASIS] = {0.f, 0.f, 0.f, 0.f, 0.f};
    float a1[N_BASIS] = {0.f, 0.f, 0.f, 0.f, 0.f};

    if (useEll) {
        const int4* ep4 = (const int4*)(eLds + wave * ELL_CAP);  // 48*8B: 16B aligned
        int j = 0;
        for (; j + 3 < cnt; j += 4) {
            int4 E0 = ep4[(j >> 1)];
            int4 E1 = ep4[(j >> 1) + 1];
            int c0 = E0.x & 0xFFFF, sy0 = E0.x >> 16; float w0 = __int_as_float(E0.y);
            int c1 = E0.z & 0xFFFF, sy1 = E0.z >> 16; float w1 = __int_as_float(E0.w);
            int c2 = E1.x & 0xFFFF, sy2 = E1.x >> 16; float w2 = __int_as_float(E1.y);
            int c3 = E1.z & 0xFFFF, sy3 = E1.z >> 16; float w3 = __int_as_float(E1.w);
            float2 x0 = __bfloat1622float2(xTb[c0 * 64 + lane]);   // 4 gathers in flight
            float2 x1 = __bfloat1622float2(xTb[c1 * 64 + lane]);
            float2 x2 = __bfloat1622float2(xTb[c2 * 64 + lane]);
            float2 x3 = __bfloat1622float2(xTb[c3 * 64 + lane]);
            float4 fA0 = *(const float4*)&facsP[sy0 * 8]; float f40 = facsP[sy0 * 8 + 4];
            float4 fA1 = *(const float4*)&facsP[sy1 * 8]; float f41 = facsP[sy1 * 8 + 4];
            float4 fA2 = *(const float4*)&facsP[sy2 * 8]; float f42 = facsP[sy2 * 8 + 4];
            float4 fA3 = *(const float4*)&facsP[sy3 * 8]; float f43 = facsP[sy3 * 8 + 4];
            float2 xw0 = make_float2(x0.x * w0, x0.y * w0);
            float2 xw1 = make_float2(x1.x * w1, x1.y * w1);
            float2 xw2 = make_float2(x2.x * w2, x2.y * w2);
            float2 xw3 = make_float2(x3.x * w3, x3.y * w3);
            EDGE_FMA(xw0, fA0, f40)
            EDGE_FMA(xw1, fA1, f41)
            EDGE_FMA(xw2, fA2, f42)
            EDGE_FMA(xw3, fA3, f43)
        }
        for (; j < cnt; ++j) {
            int2 e = eLds[wave * ELL_CAP + j];
            int c = e.x & 0xFFFF, sy = e.x >> 16;
            float w = __int_as_float(e.y);
            float2 x = __bfloat1622float2(xTb[c * 64 + lane]);
            float4 fA = *(const float4*)&facsP[sy * 8]; float f4 = facsP[sy * 8 + 4];
            float2 xw = make_float2(x.x * w, x.y * w);
            EDGE_FMA(xw, fA, f4)
        }
    } else {
        // CSR fallback: edges read directly from global (safety path)
        const int2* ep = edges + rowStart[n];
        int j = 0;
        for (; j + 1 < cnt; j += 2) {
            int2 e0 = ep[j];
            int2 e1 = ep[j + 1];
            int c0 = e0.x & 0xFFFF, sy0 = e0.x >> 16;
            int c1 = e1.x & 0xFFFF, sy1 = e1.x >> 16;
            float2 x0 = __bfloat1622float2(xTb[c0 * 64 + lane]);
            float2 x1 = __bfloat1622float2(xTb[c1 * 64 + lane]);
            float w0 = __int_as_float(e0.y);
            float w1 = __int_as_float(e1.y);
            float4 fA0 = *(const float4*)&facsP[sy0 * 8]; float f40 = facsP[sy0 * 8 + 4];
            float4 fA1 = *(const float4*)&facsP[sy1 * 8]; float f41 = facsP[sy1 * 8 + 4];
            float2 xw0 = make_float2(x0.x * w0, x0.y * w0);
            float2 xw1 = make_float2(x1.x * w1, x1.y * w1);
            EDGE_FMA(xw0, fA0, f40)
            EDGE_FMA(xw1, fA1, f41)
        }
        if (j < cnt) {
            int2 e0 = ep[j];
            int c0 = e0.x & 0xFFFF, sy0 = e0.x >> 16;
            float2 x0 = __bfloat1622float2(xTb[c0 * 64 + lane]);
            float w0 = __int_as_float(e0.y);
            float4 fA0 = *(const float4*)&facsP[sy0 * 8]; float f40 = facsP[sy0 * 8 + 4];
            float2 xw0 = make_float2(x0.x * w0, x0.y * w0);
            EDGE_FMA(xw0, fA0, f40)
        }
    }

#pragma unroll
    for (int r = 0; r < N_BASIS; ++r) {
        int jj = wave * 5 + r;
        accLds[jj * 133 + 2 * lane]     = a0[r];   // s = 2*lane
        accLds[jj * 133 + 2 * lane + 1] = a1[r];   // s = 2*lane+1
    }
    __syncthreads();

    // epilogue: 128 s x 40 floats = 2560 float2; contiguous 160B runs per s
    int base2 = blockIdx.x * 20;
    for (int it = 0; it < 5; ++it) {
        int flat = it * 512 + tid;          // 0..2559
        int s  = flat / 20;
        int jj = flat % 20;
        float f0 = accLds[(2 * jj) * 133 + s];
        float f1 = accLds[(2 * jj + 1) * 133 + s];
        out2[s * 125000 + base2 + jj] = make_float2(f0, f1);
    }
}

// ---------------- launcher ----------------
extern "C" void kernel_launch(void* const* d_in, const int* in_sizes, int n_in,
                              void* d_out, int out_size, void* d_ws, size_t ws_size,
                              hipStream_t stream) {
    const float* inp     = (const float*)d_in[0];   // (1,128,17400) fp32
    const int*   indices = (const int*)d_in[1];     // (800000,2)
    const float* weights = (const float*)d_in[2];   // (800000,)
    const float* sw      = (const float*)d_in[3];   // (10,5)
    const int*   syn     = (const int*)d_in[4];     // (800000,)

    char* ws = (char*)d_ws;
    __hip_bfloat162* xTb = (__hip_bfloat162*)(ws);          // 17400*64*4 = 4,454,400 B
    int* counts          = (int*)(ws + 4454400);            // 200,000 B

    const size_t ELL_BYTES_END = 4654400ULL + (size_t)N_POST * ELL_CAP * 8;  // 23,854,400
    bool useEll = (ws_size >= ELL_BYTES_END);

    if (useEll) {
        int2* ell = (int2*)(ws + 4654400);                  // 19,200,000 B (16B aligned)
        // d_out (128MB) doubles as scratch until k_compute's epilogue overwrites it:
        int2* bEdges   = (int2*)d_out;                      // 196*5120*8 = 8,028,160 B
        int*  bucketCnt = (int*)((char*)d_out + (size_t)NBKT * CAPB * 8);  // 784 B
        hipMemsetAsync(bucketCnt, 0, 1024, stream);
        k_prep<<<BIN_BLOCKS + TPOSE_BLOCKS, 256, 0, stream>>>(
            inp, xTb, (const int2*)indices, weights, syn, bucketCnt, bEdges);
        k_build<<<NBKT, 512, 0, stream>>>(bEdges, bucketCnt, ell, counts);
        k_compute<<<N_POST / 8, 512, 0, stream>>>(xTb, ell, nullptr, counts, sw,
                                                  (float2*)d_out, ELL_CAP, 1);
    } else {
        int* cursor    = (int*)(ws + 4654400);              // 200,000 B (adjacent to counts)
        int* rowStart  = (int*)(ws + 4854400);              // 200,000 B
        int* blockSums = (int*)(ws + 5054400);              // 256 B
        int* blockOffs = (int*)(ws + 5054656);              // 256 B
        int2* edges    = (int2*)(ws + 5054912);             // 6,400,000 B
        hipMemsetAsync(counts, 0, 400000, stream);          // counts + cursor
        k_transpose_bf16<<<(N_LGN + 63) / 64, 256, 0, stream>>>(inp, xTb);
        k_hist<<<(NNZ / 2 + 255) / 256, 256, 0, stream>>>((const int4*)indices, counts);
        k_scan1<<<(N_POST + 1023) / 1024, 1024, 0, stream>>>(counts, rowStart, blockSums);
        k_scan2<<<1, 64, 0, stream>>>(blockSums, blockOffs, (N_POST + 1023) / 1024);
        k_scan3<<<(N_POST + 1023) / 1024, 1024, 0, stream>>>(rowStart, blockOffs);
        k_scatter_csr<<<(NNZ / 2 + 255) / 256, 256, 0, stream>>>(
            (const int4*)indices, (const float2*)weights, (const int2*)syn,
            rowStart, cursor, edges);
        k_compute<<<N_POST / 8, 512, 0, stream>>>(xTb, edges, rowStart, counts, sw,
                                                  (float2*)d_out, 1 << 30, 0);
    }
}

// Round 6
// 205.842 us; speedup vs baseline: 2.5598x; 1.0429x over previous
//
#include <hip/hip_runtime.h>
#include <hip/hip_bf16.h>
#include <stdint.h>

#define N_LGN   17400
#define N_POST  50000
#define NNZ     800000
#define N_BASIS 5
#define ELL_CAP 48

#define NBKT      196        // row buckets of 256 rows (50000/256 -> 196)
#define CAPB      5120       // per-bucket edge capacity (mean 4082, +16 sigma)
#define BIN_CHUNK 4096
#define BIN_BLOCKS ((NNZ + BIN_CHUNK - 1) / BIN_CHUNK)          // 196

#define TPOSE_CBLK   32
#define TPOSE_BLOCKS ((N_LGN + TPOSE_CBLK - 1) / TPOSE_CBLK)    // 544

// ---------------- fused prep: bin edges (blocks [0,196)) + transpose (blocks [196,740)) --
__global__ __launch_bounds__(256) void k_prep(const float* __restrict__ inp,
                                              __hip_bfloat162* __restrict__ xTb,
                                              const int2* __restrict__ idx2,
                                              const float* __restrict__ w,
                                              const int* __restrict__ syn,
                                              int* __restrict__ bucketCnt,
                                              int2* __restrict__ bEdges) {
    __shared__ alignas(16) int2 ebuf[BIN_CHUNK];       // 32KB (transpose aliases tile here)
    __shared__ unsigned char sbuf[BIN_CHUNK];          // bucket id per buffer slot
    __shared__ int hcnt[256], hstart[256], hcur[256], gbase[256];
    int tid = threadIdx.x;
    if (blockIdx.x < BIN_BLOCKS) {
        int base = blockIdx.x * BIN_CHUNK;
        int ne = NNZ - base; if (ne > BIN_CHUNK) ne = BIN_CHUNK;
        hcnt[tid] = 0;
        __syncthreads();
        int2 pk[16]; int bk[16];
#pragma unroll
        for (int i = 0; i < 16; ++i) {
            int p = i * 256 + tid;
            bk[i] = -1;
            if (p < ne) {
                int2 rc = idx2[base + p];                  // (row, col) coalesced
                float wv = w[base + p];
                int sy = syn[base + p];
                int b  = rc.x >> 8;
                int rl = rc.x & 255;
                pk[i] = make_int2(rc.y | (sy << 15) | (rl << 19), __float_as_int(wv));
                bk[i] = b;
                atomicAdd(&hcnt[b], 1);                    // LDS histogram
            }
        }
        __syncthreads();
        int v = hcnt[tid];
        hstart[tid] = v;
        __syncthreads();
        for (int off = 1; off < 256; off <<= 1) {
            int t = (tid >= off) ? hstart[tid - off] : 0;
            __syncthreads();
            hstart[tid] += t;
            __syncthreads();
        }
        int excl = hstart[tid] - v;
        hstart[tid] = excl;
        hcur[tid]  = excl;
        if (tid < NBKT) gbase[tid] = atomicAdd(&bucketCnt[tid], v);  // one atomic per bucket
        __syncthreads();
#pragma unroll
        for (int i = 0; i < 16; ++i) {
            if (bk[i] >= 0) {
                int pos = atomicAdd(&hcur[bk[i]], 1);      // place, grouped by bucket
                ebuf[pos] = pk[i];
                sbuf[pos] = (unsigned char)bk[i];
            }
        }
        __syncthreads();
        for (int p = tid; p < ne; p += 256) {              // flush: contiguous runs per bucket
            int b  = sbuf[p];
            int gi = gbase[b] + (p - hstart[b]);
            if (gi < CAPB) bEdges[b * CAPB + gi] = ebuf[p];
        }
    } else {
        // ---- transpose x (128 x 17400) fp32 -> xTb (17400 x 64) bf16x2, 32-col tiles ----
        float* tile = (float*)ebuf;                        // 32*129*4 = 16,512B <= 32KB
        int c0 = (blockIdx.x - BIN_BLOCKS) * TPOSE_CBLK;
        for (int it = 0; it < 16; ++it) {
            int flat = it * 256 + tid;
            int s  = flat >> 5;
            int cl = flat & 31;
            int c  = c0 + cl;
            float v = 0.0f;
            if (c < N_LGN) v = inp[s * N_LGN + c];
            tile[cl * 129 + s] = v;
        }
        __syncthreads();
        for (int it = 0; it < 8; ++it) {
            int flat = it * 256 + tid;
            int cl = flat >> 6;
            int sp = flat & 63;
            int c  = c0 + cl;
            if (c < N_LGN) {
                float2 f = make_float2(tile[cl * 129 + 2 * sp], tile[cl * 129 + 2 * sp + 1]);
                xTb[c * 64 + sp] = __float22bfloat162_rn(f);
            }
        }
    }
}

// ---------------- build ELL from binned edges: all writes full-line coalesced ------------
// Slab is ZERO-INITIALIZED (col=0, w=0) so ELL pad slots are exact-zero edges: the compute
// kernel can run uniform padded loops with no per-row tail handling (pad contributes 0.0).
__global__ __launch_bounds__(512) void k_build(const int2* __restrict__ bEdges,
                                               const int* __restrict__ bucketCnt,
                                               int2* __restrict__ ell,
                                               int* __restrict__ counts) {
    __shared__ alignas(16) int2 slab[256 * ELL_CAP];   // 98,304B: 256 rows x 48 slots
    __shared__ int rcnt[256];
    int tid = threadIdx.x;
    int b   = blockIdx.x;
    if (tid < 256) rcnt[tid] = 0;
    {   // zero-fill slab (24 int4 stores/thread)
        int4* s4w = (int4*)slab;
        for (int i = tid; i < 256 * ELL_CAP / 2; i += 512) s4w[i] = make_int4(0, 0, 0, 0);
    }
    __syncthreads();
    int cnt = bucketCnt[b]; if (cnt > CAPB) cnt = CAPB;
    for (int p = tid; p < cnt; p += 512) {
        int2 e = bEdges[b * CAPB + p];                 // coalesced read
        int rl = (e.x >> 19) & 0xFF;
        int r = atomicAdd(&rcnt[rl], 1);               // LDS atomic: cheap
        if (r < ELL_CAP)
            slab[rl * ELL_CAP + r] =
                make_int2((e.x & 0x7FFF) | (((e.x >> 15) & 0xF) << 16), e.y);
    }
    __syncthreads();
    const int4* s4 = (const int4*)slab;                // slab -> global, full lines
    int4* e4 = (int4*)(ell + (size_t)b * (256 * ELL_CAP));
    for (int i = tid; i < 256 * ELL_CAP / 2; i += 512) e4[i] = s4[i];
    if (tid < 256) {
        int row = b * 256 + tid;
        if (row < N_POST) counts[row] = rcnt[tid];
    }
}

// ---------------- CSR fallback path (used only if ws too small for ELL) ----------------
__global__ __launch_bounds__(256) void k_transpose_bf16(const float* __restrict__ inp,
                                                        __hip_bfloat162* __restrict__ xTb) {
    __shared__ float tile[64 * 129];
    int c0  = blockIdx.x * 64;
    int tid = threadIdx.x;
    for (int it = 0; it < 32; ++it) {
        int flat = it * 256 + tid;
        int s  = flat >> 6;
        int cl = flat & 63;
        int c  = c0 + cl;
        float v = 0.0f;
        if (c < N_LGN) v = inp[s * N_LGN + c];
        tile[cl * 129 + s] = v;
    }
    __syncthreads();
    for (int it = 0; it < 16; ++it) {
        int flat = it * 256 + tid;
        int cl = flat >> 6;
        int sp = flat & 63;
        int c  = c0 + cl;
        if (c < N_LGN) {
            float2 f = make_float2(tile[cl * 129 + 2 * sp], tile[cl * 129 + 2 * sp + 1]);
            xTb[c * 64 + sp] = __float22bfloat162_rn(f);
        }
    }
}

__global__ __launch_bounds__(256) void k_hist(const int4* __restrict__ idx2,
                                              int* __restrict__ counts) {
    int t = blockIdx.x * 256 + threadIdx.x;
    if (t >= NNZ / 2) return;
    int4 rc = idx2[t];
    atomicAdd(&counts[rc.x], 1);
    atomicAdd(&counts[rc.z], 1);
}

__global__ __launch_bounds__(1024) void k_scan1(const int* __restrict__ counts,
                                                int* __restrict__ rowStart,
                                                int* __restrict__ blockSums) {
    __shared__ int tmp[1024];
    int tid = threadIdx.x;
    int gid = blockIdx.x * 1024 + tid;
    int v = (gid < N_POST) ? counts[gid] : 0;
    tmp[tid] = v;
    __syncthreads();
    for (int off = 1; off < 1024; off <<= 1) {
        int t = (tid >= off) ? tmp[tid - off] : 0;
        __syncthreads();
        tmp[tid] += t;
        __syncthreads();
    }
    if (gid < N_POST) rowStart[gid] = tmp[tid] - v;
    if (tid == 1023) blockSums[blockIdx.x] = tmp[1023];
}

__global__ __launch_bounds__(64) void k_scan2(const int* __restrict__ blockSums,
                                              int* __restrict__ blockOffsets, int nblk) {
    __shared__ int tmp[64];
    int tid = threadIdx.x;
    int v = (tid < nblk) ? blockSums[tid] : 0;
    tmp[tid] = v;
    __syncthreads();
    for (int off = 1; off < 64; off <<= 1) {
        int t = (tid >= off) ? tmp[tid - off] : 0;
        __syncthreads();
        tmp[tid] += t;
        __syncthreads();
    }
    if (tid < nblk) blockOffsets[tid] = tmp[tid] - v;
}

__global__ __launch_bounds__(1024) void k_scan3(int* __restrict__ rowStart,
                                                const int* __restrict__ blockOffsets) {
    int gid = blockIdx.x * 1024 + threadIdx.x;
    if (gid < N_POST) rowStart[gid] += blockOffsets[blockIdx.x];
}

__global__ __launch_bounds__(256) void k_scatter_csr(const int4* __restrict__ idx2,
                                                     const float2* __restrict__ w2,
                                                     const int2* __restrict__ syn2,
                                                     const int* __restrict__ rowStart,
                                                     int* __restrict__ cursor,
                                                     int2* __restrict__ edges) {
    int t = blockIdx.x * 256 + threadIdx.x;
    if (t >= NNZ / 2) return;
    int4 rc = idx2[t];
    float2 ww = w2[t];
    int2 sy = syn2[t];
    int p0 = rowStart[rc.x] + atomicAdd(&cursor[rc.x], 1);
    edges[p0] = make_int2(rc.y | (sy.x << 16), __float_as_int(ww.x));
    int p1 = rowStart[rc.z] + atomicAdd(&cursor[rc.z], 1);
    edges[p1] = make_int2(rc.w | (sy.y << 16), __float_as_int(ww.y));
}

// per-edge FMA body into named accumulator arrays
#define EDGE_FMA2(P0, P1, XW, FA, F4)                                             \
    P0[0] = fmaf((XW).x, (FA).x, P0[0]); P1[0] = fmaf((XW).y, (FA).x, P1[0]);     \
    P0[1] = fmaf((XW).x, (FA).y, P0[1]); P1[1] = fmaf((XW).y, (FA).y, P1[1]);     \
    P0[2] = fmaf((XW).x, (FA).z, P0[2]); P1[2] = fmaf((XW).y, (FA).z, P1[2]);     \
    P0[3] = fmaf((XW).x, (FA).w, P0[3]); P1[3] = fmaf((XW).y, (FA).w, P1[3]);     \
    P0[4] = fmaf((XW).x, (F4),   P0[4]); P1[4] = fmaf((XW).y, (F4),   P1[4]);

// decode one packed edge pair half + gather + scale
#define DECODE_GATHER(EX, EY, XW, FA, F4)                                         \
    {                                                                             \
        int c_  = (EX) & 0xFFFF; int sy_ = (EX) >> 16;                            \
        float2 x_ = __bfloat1622float2(xTb[c_ * 64 + lane]);                      \
        float w_  = __int_as_float(EY);                                           \
        FA = *(const float4*)&facsP[sy_ * 8]; F4 = facsP[sy_ * 8 + 4];            \
        XW = make_float2(x_.x * w_, x_.y * w_);                                   \
    }

// ---------------- main compute (ELL): 16 rows/block, 2 rows/wave interleaved -------------
// Two independent edge streams per wave -> 8 gathers in flight; block time tracks
// max(cntA,cntB) instead of max over 8 rows; staging/epilogue amortize over 2x work.
// Pad slots are exact zeros (k_build) so the loop is uniform to max(cntA,cntB).
__global__ __launch_bounds__(512, 6) void k_compute_ell(const __hip_bfloat162* __restrict__ xTb,
                                                        const int2* __restrict__ ell,
                                                        const int* __restrict__ counts,
                                                        const float* __restrict__ sw,
                                                        float2* __restrict__ out2) {
    __shared__ alignas(16) float facsP[80];          // synaptic_weights 10x5, padded to 10x8
    __shared__ float accLds[40 * 133];               // reused for both 8-row phases
    __shared__ alignas(16) int2 eLds[16 * ELL_CAP];  // 16 rows x 48 slots = 6144B
    int tid  = threadIdx.x;
    int wave = tid >> 6;
    int lane = tid & 63;
    int n0   = blockIdx.x * 16;                      // 3125*16 == 50000 exactly

    if (tid < 50) facsP[(tid / 5) * 8 + (tid % 5)] = sw[tid];
    if (tid < 16 * ELL_CAP / 2)                      // 384 threads x int4 = 6144B coalesced
        ((int4*)eLds)[tid] = ((const int4*)(ell + (size_t)n0 * ELL_CAP))[tid];
    int cA = counts[n0 + wave];     if (cA > ELL_CAP) cA = ELL_CAP;
    int cB = counts[n0 + 8 + wave]; if (cB > ELL_CAP) cB = ELL_CAP;
    __syncthreads();

    float aA0[N_BASIS] = {0.f, 0.f, 0.f, 0.f, 0.f};
    float aA1[N_BASIS] = {0.f, 0.f, 0.f, 0.f, 0.f};
    float aB0[N_BASIS] = {0.f, 0.f, 0.f, 0.f, 0.f};
    float aB1[N_BASIS] = {0.f, 0.f, 0.f, 0.f, 0.f};

    const int4* epA = (const int4*)(eLds + wave * ELL_CAP);        // 2 edges per int4
    const int4* epB = (const int4*)(eLds + (wave + 8) * ELL_CAP);
    int mc = cA > cB ? cA : cB;
    for (int j = 0; j < mc; j += 4) {
        int h = j >> 1;
        int4 A0 = epA[h], A1 = epA[h + 1];
        int4 B0 = epB[h], B1 = epB[h + 1];
        float2 xwA0, xwA1, xwA2, xwA3, xwB0, xwB1, xwB2, xwB3;
        float4 fAA0, fAA1, fAA2, fAA3, fAB0, fAB1, fAB2, fAB3;
        float  f4A0, f4A1, f4A2, f4A3, f4B0, f4B1, f4B2, f4B3;
        DECODE_GATHER(A0.x, A0.y, xwA0, fAA0, f4A0)   // 8 independent gathers in flight
        DECODE_GATHER(A0.z, A0.w, xwA1, fAA1, f4A1)
        DECODE_GATHER(A1.x, A1.y, xwA2, fAA2, f4A2)
        DECODE_GATHER(A1.z, A1.w, xwA3, fAA3, f4A3)
        DECODE_GATHER(B0.x, B0.y, xwB0, fAB0, f4B0)
        DECODE_GATHER(B0.z, B0.w, xwB1, fAB1, f4B1)
        DECODE_GATHER(B1.x, B1.y, xwB2, fAB2, f4B2)
        DECODE_GATHER(B1.z, B1.w, xwB3, fAB3, f4B3)
        EDGE_FMA2(aA0, aA1, xwA0, fAA0, f4A0)
        EDGE_FMA2(aA0, aA1, xwA1, fAA1, f4A1)
        EDGE_FMA2(aA0, aA1, xwA2, fAA2, f4A2)
        EDGE_FMA2(aA0, aA1, xwA3, fAA3, f4A3)
        EDGE_FMA2(aB0, aB1, xwB0, fAB0, f4B0)
        EDGE_FMA2(aB0, aB1, xwB1, fAB1, f4B1)
        EDGE_FMA2(aB0, aB1, xwB2, fAB2, f4B2)
        EDGE_FMA2(aB0, aB1, xwB3, fAB3, f4B3)
    }

    int base2 = blockIdx.x * 40;                     // 16 rows x 5 = 80 floats = 40 float2/s
    // ---- phase A: rows n0..n0+7 ----
#pragma unroll
    for (int r = 0; r < N_BASIS; ++r) {
        int jj = wave * 5 + r;
        accLds[jj * 133 + 2 * lane]     = aA0[r];
        accLds[jj * 133 + 2 * lane + 1] = aA1[r];
    }
    __syncthreads();
    for (int it = 0; it < 5; ++it) {
        int flat = it * 512 + tid;                   // 0..2559
        int s  = flat / 20;
        int jj = flat % 20;
        float f0 = accLds[(2 * jj) * 133 + s];
        float f1 = accLds[(2 * jj + 1) * 133 + s];
        out2[s * 125000 + base2 + jj] = make_float2(f0, f1);
    }
    __syncthreads();                                 // WAR: all reads done before reuse
    // ---- phase B: rows n0+8..n0+15 ----
#pragma unroll
    for (int r = 0; r < N_BASIS; ++r) {
        int jj = wave * 5 + r;
        accLds[jj * 133 + 2 * lane]     = aB0[r];
        accLds[jj * 133 + 2 * lane + 1] = aB1[r];
    }
    __syncthreads();
    for (int it = 0; it < 5; ++it) {
        int flat = it * 512 + tid;
        int s  = flat / 20;
        int jj = flat % 20;
        float f0 = accLds[(2 * jj) * 133 + s];
        float f1 = accLds[(2 * jj + 1) * 133 + s];
        out2[s * 125000 + base2 + 20 + jj] = make_float2(f0, f1);
    }
}

// per-edge FMA body (legacy CSR fallback kernel)
#define EDGE_FMA(XW, FA, F4) EDGE_FMA2(a0, a1, XW, FA, F4)

// ---------------- CSR-fallback compute: one wave per row (safety path) ------------------
__global__ __launch_bounds__(512, 8) void k_compute(const __hip_bfloat162* __restrict__ xTb,
                                                    const int2* __restrict__ edges,
                                                    const int* __restrict__ rowStart,
                                                    const int* __restrict__ counts,
                                                    const float* __restrict__ sw,
                                                    float2* __restrict__ out2) {
    __shared__ alignas(16) float facsP[80];
    __shared__ float accLds[40 * 133];
    int tid  = threadIdx.x;
    int wave = tid >> 6;
    int lane = tid & 63;
    int n    = blockIdx.x * 8 + wave;
    int cnt  = counts[n];

    if (tid < 50) facsP[(tid / 5) * 8 + (tid % 5)] = sw[tid];
    __syncthreads();

    float a0[N_BASIS] = {0.f, 0.f, 0.f, 0.f, 0.f};
    float a1[N_BASIS] = {0.f, 0.f, 0.f, 0.f, 0.f};

    const int2* ep = edges + rowStart[n];
    int j = 0;
    for (; j + 1 < cnt; j += 2) {
        int2 e0 = ep[j];
        int2 e1 = ep[j + 1];
        float2 xw0, xw1; float4 fA0, fA1; float f40, f41;
        DECODE_GATHER(e0.x, e0.y, xw0, fA0, f40)
        DECODE_GATHER(e1.x, e1.y, xw1, fA1, f41)
        EDGE_FMA(xw0, fA0, f40)
        EDGE_FMA(xw1, fA1, f41)
    }
    if (j < cnt) {
        int2 e0 = ep[j];
        float2 xw0; float4 fA0; float f40;
        DECODE_GATHER(e0.x, e0.y, xw0, fA0, f40)
        EDGE_FMA(xw0, fA0, f40)
    }

#pragma unroll
    for (int r = 0; r < N_BASIS; ++r) {
        int jj = wave * 5 + r;
        accLds[jj * 133 + 2 * lane]     = a0[r];
        accLds[jj * 133 + 2 * lane + 1] = a1[r];
    }
    __syncthreads();

    int base2 = blockIdx.x * 20;
    for (int it = 0; it < 5; ++it) {
        int flat = it * 512 + tid;
        int s  = flat / 20;
        int jj = flat % 20;
        float f0 = accLds[(2 * jj) * 133 + s];
        float f1 = accLds[(2 * jj + 1) * 133 + s];
        out2[s * 125000 + base2 + jj] = make_float2(f0, f1);
    }
}

// ---------------- launcher ----------------
extern "C" void kernel_launch(void* const* d_in, const int* in_sizes, int n_in,
                              void* d_out, int out_size, void* d_ws, size_t ws_size,
                              hipStream_t stream) {
    const float* inp     = (const float*)d_in[0];   // (1,128,17400) fp32
    const int*   indices = (const int*)d_in[1];     // (800000,2)
    const float* weights = (const float*)d_in[2];   // (800000,)
    const float* sw      = (const float*)d_in[3];   // (10,5)
    const int*   syn     = (const int*)d_in[4];     // (800000,)

    char* ws = (char*)d_ws;
    __hip_bfloat162* xTb = (__hip_bfloat162*)(ws);          // 17400*64*4 = 4,454,400 B
    int* counts          = (int*)(ws + 4454400);            // 200,000 B

    const size_t ELL_BYTES_END = 4654400ULL + (size_t)N_POST * ELL_CAP * 8;  // 23,854,400
    bool useEll = (ws_size >= ELL_BYTES_END);

    if (useEll) {
        int2* ell = (int2*)(ws + 4654400);                  // 19,200,000 B (16B aligned)
        // d_out (128MB) doubles as scratch until k_compute_ell's epilogue overwrites it:
        int2* bEdges   = (int2*)d_out;                      // 196*5120*8 = 8,028,160 B
        int*  bucketCnt = (int*)((char*)d_out + (size_t)NBKT * CAPB * 8);  // 784 B
        hipMemsetAsync(bucketCnt, 0, 1024, stream);
        k_prep<<<BIN_BLOCKS + TPOSE_BLOCKS, 256, 0, stream>>>(
            inp, xTb, (const int2*)indices, weights, syn, bucketCnt, bEdges);
        k_build<<<NBKT, 512, 0, stream>>>(bEdges, bucketCnt, ell, counts);
        k_compute_ell<<<N_POST / 16, 512, 0, stream>>>(xTb, ell, counts, sw,
                                                       (float2*)d_out);
    } else {
        int* cursor    = (int*)(ws + 4654400);              // 200,000 B (adjacent to counts)
        int* rowStart  = (int*)(ws + 4854400);              // 200,000 B
        int* blockSums = (int*)(ws + 5054400);              // 256 B
        int* blockOffs = (int*)(ws + 5054656);              // 256 B
        int2* edges    = (int2*)(ws + 5054912);             // 6,400,000 B
        hipMemsetAsync(counts, 0, 400000, stream);          // counts + cursor
        k_transpose_bf16<<<(N_LGN + 63) / 64, 256, 0, stream>>>(inp, xTb);
        k_hist<<<(NNZ / 2 + 255) / 256, 256, 0, stream>>>((const int4*)indices, counts);
        k_scan1<<<(N_POST + 1023) / 1024, 1024, 0, stream>>>(counts, rowStart, blockSums);
        k_scan2<<<1, 64, 0, stream>>>(blockSums, blockOffs, (N_POST + 1023) / 1024);
        k_scan3<<<(N_POST + 1023) / 1024, 1024, 0, stream>>>(rowStart, blockOffs);
        k_scatter_csr<<<(NNZ / 2 + 255) / 256, 256, 0, stream>>>(
            (const int4*)indices, (const float2*)weights, (const int2*)syn,
            rowStart, cursor, edges);
        k_compute<<<N_POST / 8, 512, 0, stream>>>(xTb, edges, rowStart, counts, sw,
                                                  (float2*)d_out);
    }
}

// Round 7
// 205.598 us; speedup vs baseline: 2.5628x; 1.0012x over previous
//
#include <hip/hip_runtime.h>
#include <hip/hip_bf16.h>
#include <stdint.h>

#define N_LGN   17400
#define N_POST  50000
#define NNZ     800000
#define N_BASIS 5
#define ELL_CAP 48

#define NBKT      196        // row buckets of 256 rows (50000/256 -> 196)
#define CAPB      5120       // per-bucket edge capacity (mean 4082, +16 sigma)
#define BIN_CHUNK 4096
#define BIN_BLOCKS ((NNZ + BIN_CHUNK - 1) / BIN_CHUNK)          // 196

#define TPOSE_CBLK   32
#define TPOSE_BLOCKS ((N_LGN + TPOSE_CBLK - 1) / TPOSE_CBLK)    // 544

// ---------------- fused prep: bin edges (blocks [0,196)) + transpose (blocks [196,740)) --
__global__ __launch_bounds__(256) void k_prep(const float* __restrict__ inp,
                                              __hip_bfloat162* __restrict__ xTb,
                                              const int2* __restrict__ idx2,
                                              const float* __restrict__ w,
                                              const int* __restrict__ syn,
                                              int* __restrict__ bucketCnt,
                                              int2* __restrict__ bEdges) {
    __shared__ alignas(16) int2 ebuf[BIN_CHUNK];       // 32KB (transpose aliases tile here)
    __shared__ unsigned char sbuf[BIN_CHUNK];          // bucket id per buffer slot
    __shared__ int hcnt[256], hstart[256], hcur[256], gbase[256];
    int tid = threadIdx.x;
    if (blockIdx.x < BIN_BLOCKS) {
        int base = blockIdx.x * BIN_CHUNK;
        int ne = NNZ - base; if (ne > BIN_CHUNK) ne = BIN_CHUNK;
        hcnt[tid] = 0;
        __syncthreads();
        int2 pk[16]; int bk[16];
#pragma unroll
        for (int i = 0; i < 16; ++i) {
            int p = i * 256 + tid;
            bk[i] = -1;
            if (p < ne) {
                int2 rc = idx2[base + p];                  // (row, col) coalesced
                float wv = w[base + p];
                int sy = syn[base + p];
                int b  = rc.x >> 8;
                int rl = rc.x & 255;
                pk[i] = make_int2(rc.y | (sy << 15) | (rl << 19), __float_as_int(wv));
                bk[i] = b;
                atomicAdd(&hcnt[b], 1);                    // LDS histogram
            }
        }
        __syncthreads();
        int v = hcnt[tid];
        hstart[tid] = v;
        __syncthreads();
        for (int off = 1; off < 256; off <<= 1) {
            int t = (tid >= off) ? hstart[tid - off] : 0;
            __syncthreads();
            hstart[tid] += t;
            __syncthreads();
        }
        int excl = hstart[tid] - v;
        hstart[tid] = excl;
        hcur[tid]  = excl;
        if (tid < NBKT) gbase[tid] = atomicAdd(&bucketCnt[tid], v);  // one atomic per bucket
        __syncthreads();
#pragma unroll
        for (int i = 0; i < 16; ++i) {
            if (bk[i] >= 0) {
                int pos = atomicAdd(&hcur[bk[i]], 1);      // place, grouped by bucket
                ebuf[pos] = pk[i];
                sbuf[pos] = (unsigned char)bk[i];
            }
        }
        __syncthreads();
        for (int p = tid; p < ne; p += 256) {              // flush: contiguous runs per bucket
            int b  = sbuf[p];
            int gi = gbase[b] + (p - hstart[b]);
            if (gi < CAPB) bEdges[b * CAPB + gi] = ebuf[p];
        }
    } else {
        // ---- transpose x (128 x 17400) fp32 -> xTb (17400 x 64) bf16x2, 32-col tiles ----
        float* tile = (float*)ebuf;                        // 32*129*4 = 16,512B <= 32KB
        int c0 = (blockIdx.x - BIN_BLOCKS) * TPOSE_CBLK;
        for (int it = 0; it < 16; ++it) {
            int flat = it * 256 + tid;
            int s  = flat >> 5;
            int cl = flat & 31;
            int c  = c0 + cl;
            float v = 0.0f;
            if (c < N_LGN) v = inp[s * N_LGN + c];
            tile[cl * 129 + s] = v;
        }
        __syncthreads();
        for (int it = 0; it < 8; ++it) {
            int flat = it * 256 + tid;
            int cl = flat >> 6;
            int sp = flat & 63;
            int c  = c0 + cl;
            if (c < N_LGN) {
                float2 f = make_float2(tile[cl * 129 + 2 * sp], tile[cl * 129 + 2 * sp + 1]);
                xTb[c * 64 + sp] = __float22bfloat162_rn(f);
            }
        }
    }
}

// ---------------- build ELL from binned edges: all writes full-line coalesced ------------
// Slab is ZERO-INITIALIZED (col=0, w=0) so ELL pad slots are exact-zero edges: the compute
// kernel can run uniform padded loops with no per-row tail handling (pad contributes 0.0).
__global__ __launch_bounds__(512) void k_build(const int2* __restrict__ bEdges,
                                               const int* __restrict__ bucketCnt,
                                               int2* __restrict__ ell,
                                               int* __restrict__ counts) {
    __shared__ alignas(16) int2 slab[256 * ELL_CAP];   // 98,304B: 256 rows x 48 slots
    __shared__ int rcnt[256];
    int tid = threadIdx.x;
    int b   = blockIdx.x;
    if (tid < 256) rcnt[tid] = 0;
    {   // zero-fill slab (24 int4 stores/thread)
        int4* s4w = (int4*)slab;
        for (int i = tid; i < 256 * ELL_CAP / 2; i += 512) s4w[i] = make_int4(0, 0, 0, 0);
    }
    __syncthreads();
    int cnt = bucketCnt[b]; if (cnt > CAPB) cnt = CAPB;
    for (int p = tid; p < cnt; p += 512) {
        int2 e = bEdges[b * CAPB + p];                 // coalesced read
        int rl = (e.x >> 19) & 0xFF;
        int r = atomicAdd(&rcnt[rl], 1);               // LDS atomic: cheap
        if (r < ELL_CAP)
            slab[rl * ELL_CAP + r] =
                make_int2((e.x & 0x7FFF) | (((e.x >> 15) & 0xF) << 16), e.y);
    }
    __syncthreads();
    const int4* s4 = (const int4*)slab;                // slab -> global, full lines
    int4* e4 = (int4*)(ell + (size_t)b * (256 * ELL_CAP));
    for (int i = tid; i < 256 * ELL_CAP / 2; i += 512) e4[i] = s4[i];
    if (tid < 256) {
        int row = b * 256 + tid;
        if (row < N_POST) counts[row] = rcnt[tid];
    }
}

// ---------------- CSR fallback path (used only if ws too small for ELL) ----------------
__global__ __launch_bounds__(256) void k_transpose_bf16(const float* __restrict__ inp,
                                                        __hip_bfloat162* __restrict__ xTb) {
    __shared__ float tile[64 * 129];
    int c0  = blockIdx.x * 64;
    int tid = threadIdx.x;
    for (int it = 0; it < 32; ++it) {
        int flat = it * 256 + tid;
        int s  = flat >> 6;
        int cl = flat & 63;
        int c  = c0 + cl;
        float v = 0.0f;
        if (c < N_LGN) v = inp[s * N_LGN + c];
        tile[cl * 129 + s] = v;
    }
    __syncthreads();
    for (int it = 0; it < 16; ++it) {
        int flat = it * 256 + tid;
        int cl = flat >> 6;
        int sp = flat & 63;
        int c  = c0 + cl;
        if (c < N_LGN) {
            float2 f = make_float2(tile[cl * 129 + 2 * sp], tile[cl * 129 + 2 * sp + 1]);
            xTb[c * 64 + sp] = __float22bfloat162_rn(f);
        }
    }
}

__global__ __launch_bounds__(256) void k_hist(const int4* __restrict__ idx2,
                                              int* __restrict__ counts) {
    int t = blockIdx.x * 256 + threadIdx.x;
    if (t >= NNZ / 2) return;
    int4 rc = idx2[t];
    atomicAdd(&counts[rc.x], 1);
    atomicAdd(&counts[rc.z], 1);
}

__global__ __launch_bounds__(1024) void k_scan1(const int* __restrict__ counts,
                                                int* __restrict__ rowStart,
                                                int* __restrict__ blockSums) {
    __shared__ int tmp[1024];
    int tid = threadIdx.x;
    int gid = blockIdx.x * 1024 + tid;
    int v = (gid < N_POST) ? counts[gid] : 0;
    tmp[tid] = v;
    __syncthreads();
    for (int off = 1; off < 1024; off <<= 1) {
        int t = (tid >= off) ? tmp[tid - off] : 0;
        __syncthreads();
        tmp[tid] += t;
        __syncthreads();
    }
    if (gid < N_POST) rowStart[gid] = tmp[tid] - v;
    if (tid == 1023) blockSums[blockIdx.x] = tmp[1023];
}

__global__ __launch_bounds__(64) void k_scan2(const int* __restrict__ blockSums,
                                              int* __restrict__ blockOffsets, int nblk) {
    __shared__ int tmp[64];
    int tid = threadIdx.x;
    int v = (tid < nblk) ? blockSums[tid] : 0;
    tmp[tid] = v;
    __syncthreads();
    for (int off = 1; off < 64; off <<= 1) {
        int t = (tid >= off) ? tmp[tid - off] : 0;
        __syncthreads();
        tmp[tid] += t;
        __syncthreads();
    }
    if (tid < nblk) blockOffsets[tid] = tmp[tid] - v;
}

__global__ __launch_bounds__(1024) void k_scan3(int* __restrict__ rowStart,
                                                const int* __restrict__ blockOffsets) {
    int gid = blockIdx.x * 1024 + threadIdx.x;
    if (gid < N_POST) rowStart[gid] += blockOffsets[blockIdx.x];
}

__global__ __launch_bounds__(256) void k_scatter_csr(const int4* __restrict__ idx2,
                                                     const float2* __restrict__ w2,
                                                     const int2* __restrict__ syn2,
                                                     const int* __restrict__ rowStart,
                                                     int* __restrict__ cursor,
                                                     int2* __restrict__ edges) {
    int t = blockIdx.x * 256 + threadIdx.x;
    if (t >= NNZ / 2) return;
    int4 rc = idx2[t];
    float2 ww = w2[t];
    int2 sy = syn2[t];
    int p0 = rowStart[rc.x] + atomicAdd(&cursor[rc.x], 1);
    edges[p0] = make_int2(rc.y | (sy.x << 16), __float_as_int(ww.x));
    int p1 = rowStart[rc.z] + atomicAdd(&cursor[rc.z], 1);
    edges[p1] = make_int2(rc.w | (sy.y << 16), __float_as_int(ww.y));
}

// per-edge FMA body into named accumulator arrays
#define EDGE_FMA2(P0, P1, XW, FA, F4)                                             \
    P0[0] = fmaf((XW).x, (FA).x, P0[0]); P1[0] = fmaf((XW).y, (FA).x, P1[0]);     \
    P0[1] = fmaf((XW).x, (FA).y, P0[1]); P1[1] = fmaf((XW).y, (FA).y, P1[1]);     \
    P0[2] = fmaf((XW).x, (FA).z, P0[2]); P1[2] = fmaf((XW).y, (FA).z, P1[2]);     \
    P0[3] = fmaf((XW).x, (FA).w, P0[3]); P1[3] = fmaf((XW).y, (FA).w, P1[3]);     \
    P0[4] = fmaf((XW).x, (F4),   P0[4]); P1[4] = fmaf((XW).y, (F4),   P1[4]);

// factor-read + scale + FMA for one stream (consumes already-gathered x)
#define FINISH_STREAM(P0, P1, X, EX, EY)                                          \
    {                                                                             \
        int sy_  = (EX) >> 16;                                                    \
        float w_ = __int_as_float(EY);                                            \
        float4 fA_ = *(const float4*)&facsP[sy_ * 8];                             \
        float  f4_ = facsP[sy_ * 8 + 4];                                          \
        float2 xw_ = make_float2((X).x * w_, (X).y * w_);                         \
        EDGE_FMA2(P0, P1, xw_, fA_, f4_)                                          \
    }

// ---------------- main compute (ELL): 16 rows/block, 2 rows/wave, low-VGPR ---------------
// 2 edges per row per iteration (4 independent gathers, one int4 per row). Factors are
// read per-stream AFTER the gathers so peak live regs stay ~50 -> fits the 64-VGPR cap of
// __launch_bounds__(512,8): 8 waves/EU, 32 waves/CU. Latency hidden by TLP (8 waves x 4
// gathers per SIMD) instead of per-wave ILP that spilled at (512,6).
// Pad slots are exact zeros (k_build) so the loop is uniform to max(cntA,cntB).
__global__ __launch_bounds__(512, 8) void k_compute_ell(const __hip_bfloat162* __restrict__ xTb,
                                                        const int2* __restrict__ ell,
                                                        const int* __restrict__ counts,
                                                        const float* __restrict__ sw,
                                                        float2* __restrict__ out2) {
    __shared__ alignas(16) float facsP[80];          // synaptic_weights 10x5, padded to 10x8
    __shared__ float accLds[40 * 133];               // reused for both 8-row phases
    __shared__ alignas(16) int2 eLds[16 * ELL_CAP];  // 16 rows x 48 slots = 6144B
    int tid  = threadIdx.x;
    int wave = tid >> 6;
    int lane = tid & 63;
    int n0   = blockIdx.x * 16;                      // 3125*16 == 50000 exactly

    if (tid < 50) facsP[(tid / 5) * 8 + (tid % 5)] = sw[tid];
    if (tid < 16 * ELL_CAP / 2)                      // 384 threads x int4 = 6144B coalesced
        ((int4*)eLds)[tid] = ((const int4*)(ell + (size_t)n0 * ELL_CAP))[tid];
    int cA = counts[n0 + wave];     if (cA > ELL_CAP) cA = ELL_CAP;
    int cB = counts[n0 + 8 + wave]; if (cB > ELL_CAP) cB = ELL_CAP;
    __syncthreads();

    float aA0[N_BASIS] = {0.f, 0.f, 0.f, 0.f, 0.f};
    float aA1[N_BASIS] = {0.f, 0.f, 0.f, 0.f, 0.f};
    float aB0[N_BASIS] = {0.f, 0.f, 0.f, 0.f, 0.f};
    float aB1[N_BASIS] = {0.f, 0.f, 0.f, 0.f, 0.f};

    const int4* epA = (const int4*)(eLds + wave * ELL_CAP);        // 2 edges per int4
    const int4* epB = (const int4*)(eLds + (wave + 8) * ELL_CAP);
    int mc = cA > cB ? cA : cB;
    for (int j = 0; j < mc; j += 2) {
        int h = j >> 1;
        int4 A = epA[h];                             // row A edges j, j+1
        int4 B = epB[h];                             // row B edges j, j+1
        // 4 independent gathers issued back-to-back (256B/wave each, coalesced)
        float2 xA0 = __bfloat1622float2(xTb[(A.x & 0xFFFF) * 64 + lane]);
        float2 xA1 = __bfloat1622float2(xTb[(A.z & 0xFFFF) * 64 + lane]);
        float2 xB0 = __bfloat1622float2(xTb[(B.x & 0xFFFF) * 64 + lane]);
        float2 xB1 = __bfloat1622float2(xTb[(B.z & 0xFFFF) * 64 + lane]);
        // per-stream finish: one fA live at a time
        FINISH_STREAM(aA0, aA1, xA0, A.x, A.y)
        FINISH_STREAM(aA0, aA1, xA1, A.z, A.w)
        FINISH_STREAM(aB0, aB1, xB0, B.x, B.y)
        FINISH_STREAM(aB0, aB1, xB1, B.z, B.w)
    }

    int base2 = blockIdx.x * 40;                     // 16 rows x 5 = 80 floats = 40 float2/s
    // ---- phase A: rows n0..n0+7 ----
#pragma unroll
    for (int r = 0; r < N_BASIS; ++r) {
        int jj = wave * 5 + r;
        accLds[jj * 133 + 2 * lane]     = aA0[r];
        accLds[jj * 133 + 2 * lane + 1] = aA1[r];
    }
    __syncthreads();
    for (int it = 0; it < 5; ++it) {
        int flat = it * 512 + tid;                   // 0..2559
        int s  = flat / 20;
        int jj = flat % 20;
        float f0 = accLds[(2 * jj) * 133 + s];
        float f1 = accLds[(2 * jj + 1) * 133 + s];
        out2[s * 125000 + base2 + jj] = make_float2(f0, f1);
    }
    __syncthreads();                                 // WAR: all reads done before reuse
    // ---- phase B: rows n0+8..n0+15 ----
#pragma unroll
    for (int r = 0; r < N_BASIS; ++r) {
        int jj = wave * 5 + r;
        accLds[jj * 133 + 2 * lane]     = aB0[r];
        accLds[jj * 133 + 2 * lane + 1] = aB1[r];
    }
    __syncthreads();
    for (int it = 0; it < 5; ++it) {
        int flat = it * 512 + tid;
        int s  = flat / 20;
        int jj = flat % 20;
        float f0 = accLds[(2 * jj) * 133 + s];
        float f1 = accLds[(2 * jj + 1) * 133 + s];
        out2[s * 125000 + base2 + 20 + jj] = make_float2(f0, f1);
    }
}

// ---------------- CSR-fallback compute: one wave per row (safety path) ------------------
__global__ __launch_bounds__(512, 8) void k_compute(const __hip_bfloat162* __restrict__ xTb,
                                                    const int2* __restrict__ edges,
                                                    const int* __restrict__ rowStart,
                                                    const int* __restrict__ counts,
                                                    const float* __restrict__ sw,
                                                    float2* __restrict__ out2) {
    __shared__ alignas(16) float facsP[80];
    __shared__ float accLds[40 * 133];
    int tid  = threadIdx.x;
    int wave = tid >> 6;
    int lane = tid & 63;
    int n    = blockIdx.x * 8 + wave;
    int cnt  = counts[n];

    if (tid < 50) facsP[(tid / 5) * 8 + (tid % 5)] = sw[tid];
    __syncthreads();

    float a0[N_BASIS] = {0.f, 0.f, 0.f, 0.f, 0.f};
    float a1[N_BASIS] = {0.f, 0.f, 0.f, 0.f, 0.f};

    const int2* ep = edges + rowStart[n];
    int j = 0;
    for (; j + 1 < cnt; j += 2) {
        int2 e0 = ep[j];
        int2 e1 = ep[j + 1];
        float2 x0 = __bfloat1622float2(xTb[(e0.x & 0xFFFF) * 64 + lane]);
        float2 x1 = __bfloat1622float2(xTb[(e1.x & 0xFFFF) * 64 + lane]);
        FINISH_STREAM(a0, a1, x0, e0.x, e0.y)
        FINISH_STREAM(a0, a1, x1, e1.x, e1.y)
    }
    if (j < cnt) {
        int2 e0 = ep[j];
        float2 x0 = __bfloat1622float2(xTb[(e0.x & 0xFFFF) * 64 + lane]);
        FINISH_STREAM(a0, a1, x0, e0.x, e0.y)
    }

#pragma unroll
    for (int r = 0; r < N_BASIS; ++r) {
        int jj = wave * 5 + r;
        accLds[jj * 133 + 2 * lane]     = a0[r];
        accLds[jj * 133 + 2 * lane + 1] = a1[r];
    }
    __syncthreads();

    int base2 = blockIdx.x * 20;
    for (int it = 0; it < 5; ++it) {
        int flat = it * 512 + tid;
        int s  = flat / 20;
        int jj = flat % 20;
        float f0 = accLds[(2 * jj) * 133 + s];
        float f1 = accLds[(2 * jj + 1) * 133 + s];
        out2[s * 125000 + base2 + jj] = make_float2(f0, f1);
    }
}

// ---------------- launcher ----------------
extern "C" void kernel_launch(void* const* d_in, const int* in_sizes, int n_in,
                              void* d_out, int out_size, void* d_ws, size_t ws_size,
                              hipStream_t stream) {
    const float* inp     = (const float*)d_in[0];   // (1,128,17400) fp32
    const int*   indices = (const int*)d_in[1];     // (800000,2)
    const float* weights = (const float*)d_in[2];   // (800000,)
    const float* sw      = (const float*)d_in[3];   // (10,5)
    const int*   syn     = (const int*)d_in[4];     // (800000,)

    char* ws = (char*)d_ws;
    __hip_bfloat162* xTb = (__hip_bfloat162*)(ws);          // 17400*64*4 = 4,454,400 B
    int* counts          = (int*)(ws + 4454400);            // 200,000 B

    const size_t ELL_BYTES_END = 4654400ULL + (size_t)N_POST * ELL_CAP * 8;  // 23,854,400
    bool useEll = (ws_size >= ELL_BYTES_END);

    if (useEll) {
        int2* ell = (int2*)(ws + 4654400);                  // 19,200,000 B (16B aligned)
        // d_out (128MB) doubles as scratch until k_compute_ell's epilogue overwrites it:
        int2* bEdges   = (int2*)d_out;                      // 196*5120*8 = 8,028,160 B
        int*  bucketCnt = (int*)((char*)d_out + (size_t)NBKT * CAPB * 8);  // 784 B
        hipMemsetAsync(bucketCnt, 0, 1024, stream);
        k_prep<<<BIN_BLOCKS + TPOSE_BLOCKS, 256, 0, stream>>>(
            inp, xTb, (const int2*)indices, weights, syn, bucketCnt, bEdges);
        k_build<<<NBKT, 512, 0, stream>>>(bEdges, bucketCnt, ell, counts);
        k_compute_ell<<<N_POST / 16, 512, 0, stream>>>(xTb, ell, counts, sw,
                                                       (float2*)d_out);
    } else {
        int* cursor    = (int*)(ws + 4654400);              // 200,000 B (adjacent to counts)
        int* rowStart  = (int*)(ws + 4854400);              // 200,000 B
        int* blockSums = (int*)(ws + 5054400);              // 256 B
        int* blockOffs = (int*)(ws + 5054656);              // 256 B
        int2* edges    = (int2*)(ws + 5054912);             // 6,400,000 B
        hipMemsetAsync(counts, 0, 400000, stream);          // counts + cursor
        k_transpose_bf16<<<(N_LGN + 63) / 64, 256, 0, stream>>>(inp, xTb);
        k_hist<<<(NNZ / 2 + 255) / 256, 256, 0, stream>>>((const int4*)indices, counts);
        k_scan1<<<(N_POST + 1023) / 1024, 1024, 0, stream>>>(counts, rowStart, blockSums);
        k_scan2<<<1, 64, 0, stream>>>(blockSums, blockOffs, (N_POST + 1023) / 1024);
        k_scan3<<<(N_POST + 1023) / 1024, 1024, 0, stream>>>(rowStart, blockOffs);
        k_scatter_csr<<<(NNZ / 2 + 255) / 256, 256, 0, stream>>>(
            (const int4*)indices, (const float2*)weights, (const int2*)syn,
            rowStart, cursor, edges);
        k_compute<<<N_POST / 8, 512, 0, stream>>>(xTb, edges, rowStart, counts, sw,
                                                  (float2*)d_out);
    }
}